// Round 1
// baseline (5306.605 us; speedup 1.0000x reference)
//
#include <hip/hip_runtime.h>
#include <math.h>

#define DNUM 4000
#define TNUM 2000
#define FEAT 256
#define UNITS 200
#define TOPK 10

// ---------------- small utility kernels ----------------

__global__ void fill_zero_k(float* __restrict__ p, int n) {
    int i = blockIdx.x * 256 + threadIdx.x;
    if (i < n) p[i] = 0.f;
}

// out[r] = rsqrt(safe(sum_j A[r, j])), one block per row
__global__ void rowsum_rsqrt_k(const float* __restrict__ A, int cols, float* __restrict__ out) {
    int r = blockIdx.x;
    int tid = threadIdx.x;
    const float* row = A + (size_t)r * cols;
    float s = 0.f;
    for (int j = tid; j < cols; j += 256) s += row[j];
    __shared__ float red[256];
    red[tid] = s;
    __syncthreads();
    for (int st = 128; st > 0; st >>= 1) {
        if (tid < st) red[tid] += red[tid + st];
        __syncthreads();
    }
    if (tid == 0) {
        float n = red[0];
        out[r] = (n == 0.f) ? 1.f : (1.f / sqrtf(n));
    }
}

// partial column sums with atomics; out must be zeroed first
__global__ void colsum_partial_k(const float* __restrict__ A, int rows, int cols,
                                 float* __restrict__ out) {
    int j = blockIdx.x * 256 + threadIdx.x;
    if (j >= cols) return;
    int chunk = blockIdx.y, nch = gridDim.y;
    int r0 = (int)((long long)rows * chunk / nch);
    int r1 = (int)((long long)rows * (chunk + 1) / nch);
    float s = 0.f;
    for (int i = r0; i < r1; i++) s += A[(size_t)i * cols + j];
    atomicAdd(&out[j], s);
}

__global__ void rsqrt_safe_k(float* __restrict__ v, int n) {
    int i = blockIdx.x * 256 + threadIdx.x;
    if (i < n) {
        float x = v[i];
        v[i] = (x == 0.f) ? 1.f : (1.f / sqrtf(x));
    }
}

// dst[i*ldc + f] = src[i*F + f]  (concat slice-0 copy), one block per row
__global__ void copy_rows_k(const float* __restrict__ src, int F,
                            float* __restrict__ dst, int ldc) {
    int i = blockIdx.x;
    for (int f = threadIdx.x; f < F; f += 256)
        dst[(size_t)i * ldc + f] = src[(size_t)i * F + f];
}

// ---------------- top-k (k=10) per row, stable-argsort tie semantics ----------------
// S: [rows, cols] (cols <= 2048). Writes tv/ti [rows,10] and rd[r]=rsqrt(safe(sum of kept)).
__global__ void topk_k(const float* __restrict__ S, int cols,
                       float* __restrict__ tv, int* __restrict__ ti,
                       float* __restrict__ rd) {
    int row = blockIdx.x;
    int tid = threadIdx.x;
    const float* srow = S + (size_t)row * cols;
    __shared__ float vals[2048];
    __shared__ float redv[256];
    __shared__ int   redi[256];
    __shared__ float selv[TOPK];
    __shared__ int   seli[TOPK];
    for (int j = tid; j < cols; j += 256) vals[j] = srow[j];
    __syncthreads();
    for (int it = 0; it < TOPK; ++it) {
        float bv = -3.0e38f;
        int bi = 0x7fffffff;
        for (int j = tid; j < cols; j += 256) {
            float v = vals[j];
            if (v > bv || (v == bv && j < bi)) { bv = v; bi = j; }
        }
        redv[tid] = bv; redi[tid] = bi;
        __syncthreads();
        for (int st = 128; st > 0; st >>= 1) {
            if (tid < st) {
                float v2 = redv[tid + st]; int i2 = redi[tid + st];
                if (v2 > redv[tid] || (v2 == redv[tid] && i2 < redi[tid])) {
                    redv[tid] = v2; redi[tid] = i2;
                }
            }
            __syncthreads();
        }
        if (tid == 0) {
            selv[it] = redv[0];
            seli[it] = redi[0];
            vals[redi[0]] = -3.0e38f;
        }
        __syncthreads();
    }
    if (tid < TOPK) {
        tv[(size_t)row * TOPK + tid] = selv[tid];
        ti[(size_t)row * TOPK + tid] = seli[tid];
    }
    if (tid == 0) {
        float s = 0.f;
        for (int m = 0; m < TOPK; m++) s += selv[m];
        rd[row] = (s == 0.f) ? 1.f : (1.f / sqrtf(s));
    }
}

// nt[ti[g]] += tv[g] over all kept entries (column sums of sparse R_flt)
__global__ void scatter_colsum_k(const float* __restrict__ tv, const int* __restrict__ ti,
                                 float* __restrict__ nt, int n) {
    int g = blockIdx.x * 256 + threadIdx.x;
    if (g < n) atomicAdd(&nt[ti[g]], tv[g]);
}

// H_dt[i,f] = relu(rd[i] * sum_m tv[i,m]*rt[idx]*ht[idx,f]) -> C[i*ldc + coloff + f]
__global__ void gather_hdt_k(const float* __restrict__ tv, const int* __restrict__ ti,
                             const float* __restrict__ rt, const float* __restrict__ rd,
                             const float* __restrict__ ht, int F,
                             float* __restrict__ C, int ldc, int coloff) {
    int i = blockIdx.x;
    int tid = threadIdx.x;
    __shared__ float w[TOPK];
    __shared__ int   id[TOPK];
    if (tid < TOPK) {
        int idx = ti[(size_t)i * TOPK + tid];
        id[tid] = idx;
        w[tid] = tv[(size_t)i * TOPK + tid] * rt[idx];
    }
    __syncthreads();
    float s = rd[i];
    for (int f = tid; f < F; f += 256) {
        float acc = 0.f;
#pragma unroll
        for (int m = 0; m < TOPK; ++m)
            acc += w[m] * ht[(size_t)id[m] * F + f];
        C[(size_t)i * ldc + coloff + f] = fmaxf(s * acc, 0.f);
    }
}

// accT[j,f] += tv[i,m]*rd[i]*hd[i,f]  (sparse R_flt^T @ (rd .* hd))
__global__ void scatter_htd_k(const float* __restrict__ tv, const int* __restrict__ ti,
                              const float* __restrict__ rd, const float* __restrict__ hd,
                              int F, float* __restrict__ accT) {
    int i = blockIdx.x;
    int tid = threadIdx.x;
    __shared__ float row[256];
    __shared__ float w[TOPK];
    __shared__ int   id[TOPK];
    for (int f = tid; f < F; f += 256) row[f] = hd[(size_t)i * F + f];
    if (tid < TOPK) {
        id[tid] = ti[(size_t)i * TOPK + tid];
        w[tid] = tv[(size_t)i * TOPK + tid] * rd[i];
    }
    __syncthreads();
    for (int m = 0; m < TOPK; ++m) {
        float wm = w[m];
        int j = id[m];
        for (int f = tid; f < F; f += 256)
            atomicAdd(&accT[(size_t)j * F + f], wm * row[f]);
    }
}

// Ct[j*ldc + coloff + f] = relu(rt[j]*accT[j,f])
__global__ void finalize_htd_k(const float* __restrict__ accT, const float* __restrict__ rt,
                               int F, float* __restrict__ C, int ldc, int coloff) {
    int j = blockIdx.x;
    float s = rt[j];
    for (int f = threadIdx.x; f < F; f += 256)
        C[(size_t)j * ldc + coloff + f] = fmaxf(s * accT[(size_t)j * F + f], 0.f);
}

// ---------------- generic tiled SGEMM ----------------
// C[M,N] = epi( scaleC[m] * sum_k opA(A)[m,k] * scaleB[k] * opB(B)[k,n] )
// TA: A is [K,M] accessed transposed.  TB: B is [N,K] accessed transposed.
#define BM 64
#define BN 64
#define BK 16
enum { ENONE = 0, ERELU = 1, ERELUSC = 2, ESIG = 3 };

template <bool TA, bool TB, int EPI>
__global__ __launch_bounds__(256) void gemm_k(
    int M, int N, int K,
    const float* __restrict__ A, int lda,
    const float* __restrict__ B, int ldb,
    float* __restrict__ C, int ldc,
    const float* __restrict__ scaleB,
    const float* __restrict__ scaleC) {
    __shared__ float As[BK][BM + 4];
    __shared__ float Bs[BK][BN + 4];
    int bn = blockIdx.x * BN;
    int bm = blockIdx.y * BM;
    int tid = threadIdx.x;
    int tx = tid & 15;
    int ty = tid >> 4;
    float acc[4][4] = {};
    for (int t = 0; t < K; t += BK) {
        // A tile -> As[k][m]
#pragma unroll
        for (int it = 0; it < (BM * BK) / 256; ++it) {
            int l = tid + it * 256;
            int k, m;
            if (TA) { k = l / BM; m = l % BM; }
            else    { m = l / BK; k = l % BK; }
            int gm = bm + m, gk = t + k;
            float v = 0.f;
            if (gm < M && gk < K)
                v = TA ? A[(size_t)gk * lda + gm] : A[(size_t)gm * lda + gk];
            As[k][m] = v;
        }
        // B tile -> Bs[k][n] (with optional per-k scale)
#pragma unroll
        for (int it = 0; it < (BN * BK) / 256; ++it) {
            int l = tid + it * 256;
            int k, n;
            if (TB) { n = l / BK; k = l % BK; }
            else    { k = l / BN; n = l % BN; }
            int gn = bn + n, gk = t + k;
            float v = 0.f;
            if (gn < N && gk < K) {
                v = TB ? B[(size_t)gn * ldb + gk] : B[(size_t)gk * ldb + gn];
                if (scaleB) v *= scaleB[gk];
            }
            Bs[k][n] = v;
        }
        __syncthreads();
#pragma unroll
        for (int kk = 0; kk < BK; ++kk) {
            float a[4], b[4];
#pragma unroll
            for (int i = 0; i < 4; ++i) a[i] = As[kk][ty * 4 + i];
#pragma unroll
            for (int j = 0; j < 4; ++j) b[j] = Bs[kk][tx * 4 + j];
#pragma unroll
            for (int i = 0; i < 4; ++i)
#pragma unroll
                for (int j = 0; j < 4; ++j)
                    acc[i][j] = fmaf(a[i], b[j], acc[i][j]);
        }
        __syncthreads();
    }
#pragma unroll
    for (int i = 0; i < 4; ++i) {
        int gm = bm + ty * 4 + i;
        if (gm >= M) continue;
#pragma unroll
        for (int j = 0; j < 4; ++j) {
            int gn = bn + tx * 4 + j;
            if (gn >= N) continue;
            float v = acc[i][j];
            if (EPI == ERELUSC) v = fmaxf(scaleC[gm] * v, 0.f);
            else if (EPI == ERELU) v = fmaxf(v, 0.f);
            else if (EPI == ESIG) v = 1.f / (1.f + expf(-v));
            C[(size_t)gm * ldc + gn] = v;
        }
    }
}

template <bool TA, bool TB, int EPI>
static inline void launch_gemm(int M, int N, int K,
                               const float* A, int lda,
                               const float* B, int ldb,
                               float* C, int ldc,
                               const float* sB, const float* sC,
                               hipStream_t stream) {
    dim3 grid((N + BN - 1) / BN, (M + BM - 1) / BM);
    gemm_k<TA, TB, EPI><<<grid, dim3(256), 0, stream>>>(M, N, K, A, lda, B, ldb, C, ldc, sB, sC);
}

// ---------------- driver ----------------

extern "C" void kernel_launch(void* const* d_in, const int* in_sizes, int n_in,
                              void* d_out, int out_size, void* d_ws, size_t ws_size,
                              hipStream_t stream) {
    const float* R   = (const float*)d_in[0];   // [4000,2000]
    const float* D   = (const float*)d_in[1];   // [4000,4000]
    const float* T   = (const float*)d_in[2];   // [2000,2000]
    const float* H_d = (const float*)d_in[3];   // [4000,256]
    const float* H_t = (const float*)d_in[4];   // [2000,256]
    const float* W1g[2] = {(const float*)d_in[5], (const float*)d_in[7]};
    const float* W2g[2] = {(const float*)d_in[6], (const float*)d_in[8]};
    const float* Wd[3]  = {(const float*)d_in[9],  (const float*)d_in[11], (const float*)d_in[13]};
    const float* Wt[3]  = {(const float*)d_in[10], (const float*)d_in[12], (const float*)d_in[14]};
    float* out = (float*)d_out;                 // [4000,2000], doubles as S scratch

    float* ws = (float*)d_ws;
    size_t o = 0;
    auto alloc = [&](size_t n) { float* p = ws + o; o += n; return p; };
    float* sd   = alloc(DNUM);                // rsqrt(safe(rowsum D))
    float* st   = alloc(TNUM);                // rsqrt(safe(rowsum T))
    float* rdR  = alloc(DNUM);                // bipartite norms of original R
    float* rtR  = alloc(TNUM);
    float* rd   = alloc(DNUM);                // per-level norms of sparse R_flt
    float* rt   = alloc(TNUM);
    float* hd1  = alloc((size_t)DNUM * UNITS);
    float* ht1  = alloc((size_t)TNUM * UNITS);
    float* hd2  = alloc((size_t)DNUM * UNITS);
    float* ht2  = alloc((size_t)TNUM * UNITS);
    float* GHd  = alloc((size_t)DNUM * UNITS);
    float* GHt  = alloc((size_t)TNUM * UNITS);
    float* tv   = alloc((size_t)DNUM * TOPK);
    int*   ti   = (int*)alloc((size_t)DNUM * TOPK);
    float* accT = alloc((size_t)TNUM * FEAT);
    float* Cd   = alloc((size_t)DNUM * 3 * FEAT);
    float* Ct   = alloc((size_t)TNUM * 3 * FEAT);
    (void)ws_size; (void)in_sizes; (void)n_in; (void)out_size;

    // ---- static norm vectors (reused by every level) ----
    rowsum_rsqrt_k<<<DNUM, 256, 0, stream>>>(D, DNUM, sd);
    rowsum_rsqrt_k<<<TNUM, 256, 0, stream>>>(T, TNUM, st);
    rowsum_rsqrt_k<<<DNUM, 256, 0, stream>>>(R, TNUM, rdR);
    fill_zero_k<<<(TNUM + 255) / 256, 256, 0, stream>>>(rtR, TNUM);
    colsum_partial_k<<<dim3((TNUM + 255) / 256, 32), 256, 0, stream>>>(R, DNUM, TNUM, rtR);
    rsqrt_safe_k<<<(TNUM + 255) / 256, 256, 0, stream>>>(rtR, TNUM);

    const float* hd_in = H_d;
    const float* ht_in = H_t;

    for (int l = 0; l < 2; ++l) {
        int F = (l == 0) ? FEAT : UNITS;
        int ld3 = 3 * F;
        // ---- GL layer: S = sigmoid((hd@W1) @ (ht@W2)^T), then top-k ----
        launch_gemm<false, false, ENONE>(DNUM, UNITS, F, hd_in, F, W1g[l], UNITS, GHd, UNITS, nullptr, nullptr, stream);
        launch_gemm<false, false, ENONE>(TNUM, UNITS, F, ht_in, F, W2g[l], UNITS, GHt, UNITS, nullptr, nullptr, stream);
        launch_gemm<false, true, ESIG>(DNUM, TNUM, UNITS, GHd, UNITS, GHt, UNITS, out, TNUM, nullptr, nullptr, stream);
        topk_k<<<DNUM, 256, 0, stream>>>(out, TNUM, tv, ti, rd);
        fill_zero_k<<<(TNUM + 255) / 256, 256, 0, stream>>>(rt, TNUM);
        scatter_colsum_k<<<(DNUM * TOPK + 255) / 256, 256, 0, stream>>>(tv, ti, rt, DNUM * TOPK);
        rsqrt_safe_k<<<(TNUM + 255) / 256, 256, 0, stream>>>(rt, TNUM);
        // ---- CGC layer on sparse R_flt ----
        gather_hdt_k<<<DNUM, 256, 0, stream>>>(tv, ti, rt, rd, ht_in, F, Cd, ld3, F);
        fill_zero_k<<<(TNUM * F + 255) / 256, 256, 0, stream>>>(accT, TNUM * F);
        scatter_htd_k<<<DNUM, 256, 0, stream>>>(tv, ti, rd, hd_in, F, accT);
        finalize_htd_k<<<TNUM, 256, 0, stream>>>(accT, rt, F, Ct, ld3, F);
        copy_rows_k<<<DNUM, 256, 0, stream>>>(hd_in, F, Cd, ld3);
        copy_rows_k<<<TNUM, 256, 0, stream>>>(ht_in, F, Ct, ld3);
        launch_gemm<false, false, ERELUSC>(DNUM, F, DNUM, D, DNUM, hd_in, F, Cd + 2 * F, ld3, sd, sd, stream);
        launch_gemm<false, false, ERELUSC>(TNUM, F, TNUM, T, TNUM, ht_in, F, Ct + 2 * F, ld3, st, st, stream);
        float* hdo = (l == 0) ? hd1 : hd2;
        float* hto = (l == 0) ? ht1 : ht2;
        launch_gemm<false, false, ERELU>(DNUM, UNITS, 3 * F, Cd, ld3, Wd[l], UNITS, hdo, UNITS, nullptr, nullptr, stream);
        launch_gemm<false, false, ERELU>(TNUM, UNITS, 3 * F, Ct, ld3, Wt[l], UNITS, hto, UNITS, nullptr, nullptr, stream);
        hd_in = hdo;
        ht_in = hto;
    }

    // ---- output CGC on original dense R ----
    {
        int F = UNITS, ld3 = 3 * UNITS;
        // H_dt = relu(rdR .* (R @ (rtR .* ht)))
        launch_gemm<false, false, ERELUSC>(DNUM, F, TNUM, R, TNUM, ht_in, F, Cd + F, ld3, rtR, rdR, stream);
        // H_td = relu(rtR .* (R^T @ (rdR .* hd)))
        launch_gemm<true, false, ERELUSC>(TNUM, F, DNUM, R, TNUM, hd_in, F, Ct + F, ld3, rdR, rtR, stream);
        copy_rows_k<<<DNUM, 256, 0, stream>>>(hd_in, F, Cd, ld3);
        copy_rows_k<<<TNUM, 256, 0, stream>>>(ht_in, F, Ct, ld3);
        launch_gemm<false, false, ERELUSC>(DNUM, F, DNUM, D, DNUM, hd_in, F, Cd + 2 * F, ld3, sd, sd, stream);
        launch_gemm<false, false, ERELUSC>(TNUM, F, TNUM, T, TNUM, ht_in, F, Ct + 2 * F, ld3, st, st, stream);
        launch_gemm<false, false, ERELU>(DNUM, UNITS, 3 * F, Cd, ld3, Wd[2], UNITS, hd1, UNITS, nullptr, nullptr, stream);
        launch_gemm<false, false, ERELU>(TNUM, UNITS, 3 * F, Ct, ld3, Wt[2], UNITS, ht1, UNITS, nullptr, nullptr, stream);
        // R_pred = sigmoid(hd @ ht^T)
        launch_gemm<false, true, ESIG>(DNUM, TNUM, UNITS, hd1, UNITS, ht1, UNITS, out, TNUM, nullptr, nullptr, stream);
    }
}

// Round 2
// 5286.676 us; speedup vs baseline: 1.0038x; 1.0038x over previous
//
#include <hip/hip_runtime.h>
#include <math.h>

#define DNUM 4000
#define TNUM 2000
#define FEAT 256
#define UNITS 200
#define TOPK 10

typedef __attribute__((ext_vector_type(8))) short short8;
typedef __attribute__((ext_vector_type(4))) float f32x4;

enum { ENONE = 0, ERELU = 1, ERELUSC = 2, ESIG = 3 };

typedef unsigned int u32_g __attribute__((address_space(1)));
typedef unsigned int u32_l __attribute__((address_space(3)));

__device__ __forceinline__ unsigned short f2bf(float x) {
    union { float f; unsigned u; } v; v.f = x;
    unsigned r = v.u + 0x7fffu + ((v.u >> 16) & 1u);  // RNE
    return (unsigned short)(r >> 16);
}
__device__ __forceinline__ float bf2f(unsigned short b) {
    union { float f; unsigned u; } v; v.u = ((unsigned)b) << 16; return v.f;
}
__device__ __forceinline__ void ld_lds16(const void* g, void* l) {
    __builtin_amdgcn_global_load_lds((const u32_g*)g, (u32_l*)l, 16, 0, 0);
}

// ---------------- small utility kernels ----------------

__global__ void fill_zero_k(float* __restrict__ p, int n) {
    int i = blockIdx.x * 256 + threadIdx.x;
    if (i < n) p[i] = 0.f;
}

__global__ void rowsum_rsqrt_k(const float* __restrict__ A, int cols, float* __restrict__ out) {
    int r = blockIdx.x;
    int tid = threadIdx.x;
    const float* row = A + (size_t)r * cols;
    float s = 0.f;
    for (int j = tid; j < cols; j += 256) s += row[j];
    __shared__ float red[256];
    red[tid] = s;
    __syncthreads();
    for (int st = 128; st > 0; st >>= 1) {
        if (tid < st) red[tid] += red[tid + st];
        __syncthreads();
    }
    if (tid == 0) {
        float n = red[0];
        out[r] = (n == 0.f) ? 1.f : (1.f / sqrtf(n));
    }
}

__global__ void colsum_partial_k(const float* __restrict__ A, int rows, int cols,
                                 float* __restrict__ out) {
    int j = blockIdx.x * 256 + threadIdx.x;
    if (j >= cols) return;
    int chunk = blockIdx.y, nch = gridDim.y;
    int r0 = (int)((long long)rows * chunk / nch);
    int r1 = (int)((long long)rows * (chunk + 1) / nch);
    float s = 0.f;
    for (int i = r0; i < r1; i++) s += A[(size_t)i * cols + j];
    atomicAdd(&out[j], s);
}

__global__ void rsqrt_safe_k(float* __restrict__ v, int n) {
    int i = blockIdx.x * 256 + threadIdx.x;
    if (i < n) {
        float x = v[i];
        v[i] = (x == 0.f) ? 1.f : (1.f / sqrtf(x));
    }
}

__global__ void copy_rows_k(const float* __restrict__ src, int F,
                            float* __restrict__ dst, int ldc) {
    int i = blockIdx.x;
    for (int f = threadIdx.x; f < F; f += 256)
        dst[(size_t)i * ldc + f] = src[(size_t)i * F + f];
}

// ---------------- top-k ----------------
__global__ void topk_k(const float* __restrict__ S, int cols,
                       float* __restrict__ tv, int* __restrict__ ti,
                       float* __restrict__ rd) {
    int row = blockIdx.x;
    int tid = threadIdx.x;
    const float* srow = S + (size_t)row * cols;
    __shared__ float vals[2048];
    __shared__ float redv[256];
    __shared__ int   redi[256];
    __shared__ float selv[TOPK];
    __shared__ int   seli[TOPK];
    for (int j = tid; j < cols; j += 256) vals[j] = srow[j];
    __syncthreads();
    for (int it = 0; it < TOPK; ++it) {
        float bv = -3.0e38f;
        int bi = 0x7fffffff;
        for (int j = tid; j < cols; j += 256) {
            float v = vals[j];
            if (v > bv || (v == bv && j < bi)) { bv = v; bi = j; }
        }
        redv[tid] = bv; redi[tid] = bi;
        __syncthreads();
        for (int st = 128; st > 0; st >>= 1) {
            if (tid < st) {
                float v2 = redv[tid + st]; int i2 = redi[tid + st];
                if (v2 > redv[tid] || (v2 == redv[tid] && i2 < redi[tid])) {
                    redv[tid] = v2; redi[tid] = i2;
                }
            }
            __syncthreads();
        }
        if (tid == 0) {
            selv[it] = redv[0];
            seli[it] = redi[0];
            vals[redi[0]] = -3.0e38f;
        }
        __syncthreads();
    }
    if (tid < TOPK) {
        tv[(size_t)row * TOPK + tid] = selv[tid];
        ti[(size_t)row * TOPK + tid] = seli[tid];
    }
    if (tid == 0) {
        float s = 0.f;
        for (int m = 0; m < TOPK; m++) s += selv[m];
        rd[row] = (s == 0.f) ? 1.f : (1.f / sqrtf(s));
    }
}

__global__ void scatter_colsum_k(const float* __restrict__ tv, const int* __restrict__ ti,
                                 float* __restrict__ nt, int n) {
    int g = blockIdx.x * 256 + threadIdx.x;
    if (g < n) atomicAdd(&nt[ti[g]], tv[g]);
}

__global__ void gather_hdt_k(const float* __restrict__ tv, const int* __restrict__ ti,
                             const float* __restrict__ rt, const float* __restrict__ rd,
                             const float* __restrict__ ht, int F,
                             float* __restrict__ C, int ldc, int coloff) {
    int i = blockIdx.x;
    int tid = threadIdx.x;
    __shared__ float w[TOPK];
    __shared__ int   id[TOPK];
    if (tid < TOPK) {
        int idx = ti[(size_t)i * TOPK + tid];
        id[tid] = idx;
        w[tid] = tv[(size_t)i * TOPK + tid] * rt[idx];
    }
    __syncthreads();
    float s = rd[i];
    for (int f = tid; f < F; f += 256) {
        float acc = 0.f;
#pragma unroll
        for (int m = 0; m < TOPK; ++m)
            acc += w[m] * ht[(size_t)id[m] * F + f];
        C[(size_t)i * ldc + coloff + f] = fmaxf(s * acc, 0.f);
    }
}

__global__ void scatter_htd_k(const float* __restrict__ tv, const int* __restrict__ ti,
                              const float* __restrict__ rd, const float* __restrict__ hd,
                              int F, float* __restrict__ accT) {
    int i = blockIdx.x;
    int tid = threadIdx.x;
    __shared__ float row[256];
    __shared__ float w[TOPK];
    __shared__ int   id[TOPK];
    for (int f = tid; f < F; f += 256) row[f] = hd[(size_t)i * F + f];
    if (tid < TOPK) {
        id[tid] = ti[(size_t)i * TOPK + tid];
        w[tid] = tv[(size_t)i * TOPK + tid] * rd[i];
    }
    __syncthreads();
    for (int m = 0; m < TOPK; ++m) {
        float wm = w[m];
        int j = id[m];
        for (int f = tid; f < F; f += 256)
            atomicAdd(&accT[(size_t)j * F + f], wm * row[f]);
    }
}

__global__ void finalize_htd_k(const float* __restrict__ accT, const float* __restrict__ rt,
                               int F, float* __restrict__ C, int ldc, int coloff) {
    int j = blockIdx.x;
    float s = rt[j];
    for (int f = threadIdx.x; f < F; f += 256)
        C[(size_t)j * ldc + coloff + f] = fmaxf(s * accT[(size_t)j * F + f], 0.f);
}

// ---------------- bf16-split pack kernels ----------------
// out[r][seg*Kp + c] = bf16 split #seg of X[r][c]*rs[r]*cs[c]; zero-padded.
__global__ void pack_rows_k(const float* __restrict__ X, int R, int C,
                            int Kp, int NS, int ld,
                            const float* __restrict__ rs, const float* __restrict__ cs,
                            unsigned short* __restrict__ out) {
    int r = blockIdx.x;
    unsigned short* orow = out + (size_t)r * ld;
    if (r >= R) {
        for (int c = threadIdx.x; c < NS * Kp; c += 256) orow[c] = 0;
        return;
    }
    float rsc = rs ? rs[r] : 1.f;
    const float* xrow = X + (size_t)r * C;
    for (int c = threadIdx.x; c < Kp; c += 256) {
        float v = 0.f;
        if (c < C) { v = xrow[c] * rsc; if (cs) v *= cs[c]; }
        unsigned short b0 = f2bf(v);
        float r1 = v - bf2f(b0);
        unsigned short b1 = f2bf(r1);
        orow[c] = b0;
        orow[Kp + c] = b1;
        if (NS == 3) orow[2 * Kp + c] = f2bf(r1 - bf2f(b1));
    }
}

// out[c][seg*Kp + k] = split(X[k][c]*ks[k]*ns[c]); grid (cols_alloc/32, Kp/32)
__global__ void pack_trans_k(const float* __restrict__ X, int R, int C,
                             int Kp, int NS, int ld,
                             const float* __restrict__ ks, const float* __restrict__ ns,
                             unsigned short* __restrict__ out) {
    __shared__ float tile[32][33];
    int c0 = blockIdx.x * 32, k0 = blockIdx.y * 32;
    int ci = threadIdx.x & 31, kq = threadIdx.x >> 5;
    for (int i = 0; i < 4; ++i) {
        int k = k0 + kq * 4 + i;
        int c = c0 + ci;
        float v = 0.f;
        if (k < R && c < C) {
            v = X[(size_t)k * C + c];
            if (ks) v *= ks[k];
            if (ns) v *= ns[c];
        }
        tile[kq * 4 + i][ci] = v;
    }
    __syncthreads();
    int ko = threadIdx.x & 31, cq = threadIdx.x >> 5;
    for (int i = 0; i < 4; ++i) {
        int c = cq * 4 + i;
        float v = tile[ko][c];
        unsigned short b0 = f2bf(v);
        float r1 = v - bf2f(b0);
        unsigned short b1 = f2bf(r1);
        unsigned short* o = out + (size_t)(c0 + c) * ld + (k0 + ko);
        o[0] = b0;
        o[Kp] = b1;
        if (NS == 3) o[2 * Kp] = f2bf(r1 - bf2f(b1));
    }
}

// ---------------- MFMA split-GEMM ----------------
// A [M_pad rows, ldA] bf16 (K-contig, split segs at s*Kp), B [N_pad rows, ldB] (B^T layout).
// C = sum_{i+j<MAXS} Ai Bj^T over logical K = Kp.
// grid (Nt, Mt, splits); splits>1 -> raw partials into Cpart[z][M][N]; else epilogue into dst.
template <int MAXS, int EPI>
__global__ __launch_bounds__(256) void gemm_bt_k(
    const unsigned short* __restrict__ A, int ldA,
    const unsigned short* __restrict__ B, int ldB,
    int Kp, int ktot, int splits,
    float* __restrict__ Cpart,
    float* __restrict__ dst, int ldc, int coloff,
    int M, int N) {
    __shared__ __align__(16) short As[MAXS][128 * 32];
    __shared__ __align__(16) short Bs[MAXS][128 * 32];
    int tid = threadIdx.x;
    int lane = tid & 63, wid = tid >> 6;
    int wm = wid >> 1, wn = wid & 1;
    int bm = blockIdx.y * 128, bn = blockIdx.x * 128;
    int z = blockIdx.z;
    int kt0 = (int)((long long)ktot * z / splits);
    int kt1 = (int)((long long)ktot * (z + 1) / splits);
    int r_i = lane & 15, quad = lane >> 4;
    f32x4 acc[4][4] = {};
    for (int t = kt0; t < kt1; ++t) {
        int kbase = t * 32;
#pragma unroll
        for (int s = 0; s < MAXS; ++s) {
#pragma unroll
            for (int it = 0; it < 2; ++it) {
                int flat = (it * 256 + tid) * 8;
                int row = flat >> 5;
                int ko = flat & 31;
                ld_lds16(A + (size_t)(bm + row) * ldA + s * Kp + kbase + ko, &As[s][flat]);
                ld_lds16(B + (size_t)(bn + row) * ldB + s * Kp + kbase + ko, &Bs[s][flat]);
            }
        }
        __syncthreads();
        short8 af[MAXS][4], bfr[MAXS][4];
#pragma unroll
        for (int s = 0; s < MAXS; ++s)
#pragma unroll
            for (int mi = 0; mi < 4; ++mi) {
                af[s][mi]  = *(const short8*)&As[s][(wm * 64 + mi * 16 + r_i) * 32 + quad * 8];
                bfr[s][mi] = *(const short8*)&Bs[s][(wn * 64 + mi * 16 + r_i) * 32 + quad * 8];
            }
#pragma unroll
        for (int i = 0; i < MAXS; ++i)
#pragma unroll
            for (int j = 0; j < MAXS; ++j) {
                if (i + j >= MAXS) continue;
#pragma unroll
                for (int mi = 0; mi < 4; ++mi)
#pragma unroll
                    for (int ni = 0; ni < 4; ++ni)
                        acc[mi][ni] = __builtin_amdgcn_mfma_f32_16x16x32_bf16(
                            af[i][mi], bfr[j][ni], acc[mi][ni], 0, 0, 0);
            }
        __syncthreads();
    }
#pragma unroll
    for (int mi = 0; mi < 4; ++mi)
#pragma unroll
        for (int ni = 0; ni < 4; ++ni)
#pragma unroll
            for (int r = 0; r < 4; ++r) {
                int gm = bm + wm * 64 + mi * 16 + quad * 4 + r;
                int gn = bn + wn * 64 + ni * 16 + r_i;
                if (gm >= M || gn >= N) continue;
                float v = acc[mi][ni][r];
                if (splits > 1) {
                    Cpart[((size_t)z * M + gm) * N + gn] = v;
                } else {
                    if (EPI == ERELU) v = fmaxf(v, 0.f);
                    else if (EPI == ESIG) v = 1.f / (1.f + expf(-v));
                    dst[(size_t)gm * ldc + coloff + gn] = v;
                }
            }
}

template <int EPI>
__global__ void epi_k(const float* __restrict__ Cpart, int splits, int M, int N,
                      float* __restrict__ dst, int ldc, int coloff) {
    int idx = blockIdx.x * 256 + threadIdx.x;
    if (idx >= M * N) return;
    size_t stride = (size_t)M * N;
    float v = 0.f;
    for (int s = 0; s < splits; ++s) v += Cpart[s * stride + idx];
    int m = idx / N, n = idx - m * N;
    if (EPI == ERELU) v = fmaxf(v, 0.f);
    else if (EPI == ESIG) v = 1.f / (1.f + expf(-v));
    dst[(size_t)m * ldc + coloff + n] = v;
}

// ---------------- fallback fp32 SGEMM (round-1 proven path) ----------------
#define BM 64
#define BN 64
#define BK 16

template <bool TA, bool TB, int EPI>
__global__ __launch_bounds__(256) void gemm_f32_k(
    int M, int N, int K,
    const float* __restrict__ A, int lda,
    const float* __restrict__ B, int ldb,
    float* __restrict__ C, int ldc,
    const float* __restrict__ scaleB,
    const float* __restrict__ scaleC) {
    __shared__ float Asf[BK][BM + 4];
    __shared__ float Bsf[BK][BN + 4];
    int bn = blockIdx.x * BN;
    int bm = blockIdx.y * BM;
    int tid = threadIdx.x;
    int tx = tid & 15;
    int ty = tid >> 4;
    float acc[4][4] = {};
    for (int t = 0; t < K; t += BK) {
#pragma unroll
        for (int it = 0; it < (BM * BK) / 256; ++it) {
            int l = tid + it * 256;
            int k, m;
            if (TA) { k = l / BM; m = l % BM; }
            else    { m = l / BK; k = l % BK; }
            int gm = bm + m, gk = t + k;
            float v = 0.f;
            if (gm < M && gk < K)
                v = TA ? A[(size_t)gk * lda + gm] : A[(size_t)gm * lda + gk];
            Asf[k][m] = v;
        }
#pragma unroll
        for (int it = 0; it < (BN * BK) / 256; ++it) {
            int l = tid + it * 256;
            int k, n;
            if (TB) { n = l / BK; k = l % BK; }
            else    { k = l / BN; n = l % BN; }
            int gn = bn + n, gk = t + k;
            float v = 0.f;
            if (gn < N && gk < K) {
                v = TB ? B[(size_t)gn * ldb + gk] : B[(size_t)gk * ldb + gn];
                if (scaleB) v *= scaleB[gk];
            }
            Bsf[k][n] = v;
        }
        __syncthreads();
#pragma unroll
        for (int kk = 0; kk < BK; ++kk) {
            float a[4], b[4];
#pragma unroll
            for (int i = 0; i < 4; ++i) a[i] = Asf[kk][ty * 4 + i];
#pragma unroll
            for (int j = 0; j < 4; ++j) b[j] = Bsf[kk][tx * 4 + j];
#pragma unroll
            for (int i = 0; i < 4; ++i)
#pragma unroll
                for (int j = 0; j < 4; ++j)
                    acc[i][j] = fmaf(a[i], b[j], acc[i][j]);
        }
        __syncthreads();
    }
#pragma unroll
    for (int i = 0; i < 4; ++i) {
        int gm = bm + ty * 4 + i;
        if (gm >= M) continue;
#pragma unroll
        for (int j = 0; j < 4; ++j) {
            int gn = bn + tx * 4 + j;
            if (gn >= N) continue;
            float v = acc[i][j];
            if (EPI == ERELUSC) v = fmaxf(scaleC[gm] * v, 0.f);
            else if (EPI == ERELU) v = fmaxf(v, 0.f);
            else if (EPI == ESIG) v = 1.f / (1.f + expf(-v));
            C[(size_t)gm * ldc + gn] = v;
        }
    }
}

template <bool TA, bool TB, int EPI>
static inline void launch_gemm_f32(int M, int N, int K,
                                   const float* A, int lda,
                                   const float* B, int ldb,
                                   float* C, int ldc,
                                   const float* sB, const float* sC,
                                   hipStream_t stream) {
    dim3 grid((N + BN - 1) / BN, (M + BM - 1) / BM);
    gemm_f32_k<TA, TB, EPI><<<grid, dim3(256), 0, stream>>>(M, N, K, A, lda, B, ldb, C, ldc, sB, sC);
}

// ---------------- helpers ----------------
static inline int cdiv(int a, int b) { return (a + b - 1) / b; }

template <int MAXS, int EPI>
static void mm(hipStream_t st, const unsigned short* A, int ldA,
               const unsigned short* B, int ldB, int Kp, int M, int N, int splits,
               float* Cpart, float* dst, int ldc, int coloff) {
    dim3 g(cdiv(N, 128), cdiv(M, 128), splits);
    gemm_bt_k<MAXS, EPI><<<g, 256, 0, st>>>(A, ldA, B, ldB, Kp, Kp / 32, splits,
                                            Cpart, dst, ldc, coloff, M, N);
}

template <int EPI>
static void epi(hipStream_t st, const float* Cpart, int splits, int M, int N,
                float* dst, int ldc, int coloff) {
    int n = M * N;
    epi_k<EPI><<<cdiv(n, 256), 256, 0, st>>>(Cpart, splits, M, N, dst, ldc, coloff);
}

// ---------------- fallback driver (round-1) ----------------
static void run_fp32_path(void* const* d_in, void* d_out, void* d_ws, hipStream_t stream) {
    const float* R   = (const float*)d_in[0];
    const float* D   = (const float*)d_in[1];
    const float* T   = (const float*)d_in[2];
    const float* H_d = (const float*)d_in[3];
    const float* H_t = (const float*)d_in[4];
    const float* W1g[2] = {(const float*)d_in[5], (const float*)d_in[7]};
    const float* W2g[2] = {(const float*)d_in[6], (const float*)d_in[8]};
    const float* Wd[3]  = {(const float*)d_in[9],  (const float*)d_in[11], (const float*)d_in[13]};
    const float* Wt[3]  = {(const float*)d_in[10], (const float*)d_in[12], (const float*)d_in[14]};
    float* out = (float*)d_out;
    float* ws = (float*)d_ws;
    size_t o = 0;
    auto alloc = [&](size_t n) { float* p = ws + o; o += n; return p; };
    float* sd   = alloc(DNUM);
    float* st   = alloc(TNUM);
    float* rdR  = alloc(DNUM);
    float* rtR  = alloc(TNUM);
    float* rd   = alloc(DNUM);
    float* rt   = alloc(TNUM);
    float* hd1  = alloc((size_t)DNUM * UNITS);
    float* ht1  = alloc((size_t)TNUM * UNITS);
    float* hd2  = alloc((size_t)DNUM * UNITS);
    float* ht2  = alloc((size_t)TNUM * UNITS);
    float* GHd  = alloc((size_t)DNUM * UNITS);
    float* GHt  = alloc((size_t)TNUM * UNITS);
    float* tv   = alloc((size_t)DNUM * TOPK);
    int*   ti   = (int*)alloc((size_t)DNUM * TOPK);
    float* accT = alloc((size_t)TNUM * FEAT);
    float* Cd   = alloc((size_t)DNUM * 3 * FEAT);
    float* Ct   = alloc((size_t)TNUM * 3 * FEAT);

    rowsum_rsqrt_k<<<DNUM, 256, 0, stream>>>(D, DNUM, sd);
    rowsum_rsqrt_k<<<TNUM, 256, 0, stream>>>(T, TNUM, st);
    rowsum_rsqrt_k<<<DNUM, 256, 0, stream>>>(R, TNUM, rdR);
    fill_zero_k<<<cdiv(TNUM, 256), 256, 0, stream>>>(rtR, TNUM);
    colsum_partial_k<<<dim3(cdiv(TNUM, 256), 32), 256, 0, stream>>>(R, DNUM, TNUM, rtR);
    rsqrt_safe_k<<<cdiv(TNUM, 256), 256, 0, stream>>>(rtR, TNUM);

    const float* hd_in = H_d;
    const float* ht_in = H_t;
    for (int l = 0; l < 2; ++l) {
        int F = (l == 0) ? FEAT : UNITS;
        int ld3 = 3 * F;
        launch_gemm_f32<false, false, ENONE>(DNUM, UNITS, F, hd_in, F, W1g[l], UNITS, GHd, UNITS, nullptr, nullptr, stream);
        launch_gemm_f32<false, false, ENONE>(TNUM, UNITS, F, ht_in, F, W2g[l], UNITS, GHt, UNITS, nullptr, nullptr, stream);
        launch_gemm_f32<false, true, ESIG>(DNUM, TNUM, UNITS, GHd, UNITS, GHt, UNITS, out, TNUM, nullptr, nullptr, stream);
        topk_k<<<DNUM, 256, 0, stream>>>(out, TNUM, tv, ti, rd);
        fill_zero_k<<<cdiv(TNUM, 256), 256, 0, stream>>>(rt, TNUM);
        scatter_colsum_k<<<cdiv(DNUM * TOPK, 256), 256, 0, stream>>>(tv, ti, rt, DNUM * TOPK);
        rsqrt_safe_k<<<cdiv(TNUM, 256), 256, 0, stream>>>(rt, TNUM);
        gather_hdt_k<<<DNUM, 256, 0, stream>>>(tv, ti, rt, rd, ht_in, F, Cd, ld3, F);
        fill_zero_k<<<cdiv(TNUM * F, 256), 256, 0, stream>>>(accT, TNUM * F);
        scatter_htd_k<<<DNUM, 256, 0, stream>>>(tv, ti, rd, hd_in, F, accT);
        finalize_htd_k<<<TNUM, 256, 0, stream>>>(accT, rt, F, Ct, ld3, F);
        copy_rows_k<<<DNUM, 256, 0, stream>>>(hd_in, F, Cd, ld3);
        copy_rows_k<<<TNUM, 256, 0, stream>>>(ht_in, F, Ct, ld3);
        launch_gemm_f32<false, false, ERELUSC>(DNUM, F, DNUM, D, DNUM, hd_in, F, Cd + 2 * F, ld3, sd, sd, stream);
        launch_gemm_f32<false, false, ERELUSC>(TNUM, F, TNUM, T, TNUM, ht_in, F, Ct + 2 * F, ld3, st, st, stream);
        float* hdo = (l == 0) ? hd1 : hd2;
        float* hto = (l == 0) ? ht1 : ht2;
        launch_gemm_f32<false, false, ERELU>(DNUM, UNITS, 3 * F, Cd, ld3, Wd[l], UNITS, hdo, UNITS, nullptr, nullptr, stream);
        launch_gemm_f32<false, false, ERELU>(TNUM, UNITS, 3 * F, Ct, ld3, Wt[l], UNITS, hto, UNITS, nullptr, nullptr, stream);
        hd_in = hdo;
        ht_in = hto;
    }
    {
        int F = UNITS, ld3 = 3 * UNITS;
        launch_gemm_f32<false, false, ERELUSC>(DNUM, F, TNUM, R, TNUM, ht_in, F, Cd + F, ld3, rtR, rdR, stream);
        launch_gemm_f32<true, false, ERELUSC>(TNUM, F, DNUM, R, TNUM, hd_in, F, Ct + F, ld3, rdR, rtR, stream);
        copy_rows_k<<<DNUM, 256, 0, stream>>>(hd_in, F, Cd, ld3);
        copy_rows_k<<<TNUM, 256, 0, stream>>>(ht_in, F, Ct, ld3);
        launch_gemm_f32<false, false, ERELUSC>(DNUM, F, DNUM, D, DNUM, hd_in, F, Cd + 2 * F, ld3, sd, sd, stream);
        launch_gemm_f32<false, false, ERELUSC>(TNUM, F, TNUM, T, TNUM, ht_in, F, Ct + 2 * F, ld3, st, st, stream);
        launch_gemm_f32<false, false, ERELU>(DNUM, UNITS, 3 * F, Cd, ld3, Wd[2], UNITS, hd1, UNITS, nullptr, nullptr, stream);
        launch_gemm_f32<false, false, ERELU>(TNUM, UNITS, 3 * F, Ct, ld3, Wt[2], UNITS, ht1, UNITS, nullptr, nullptr, stream);
        launch_gemm_f32<false, true, ESIG>(DNUM, TNUM, UNITS, hd1, UNITS, ht1, UNITS, out, TNUM, nullptr, nullptr, stream);
    }
}

// ---------------- main driver ----------------
extern "C" void kernel_launch(void* const* d_in, const int* in_sizes, int n_in,
                              void* d_out, int out_size, void* d_ws, size_t ws_size,
                              hipStream_t stream) {
    (void)in_sizes; (void)n_in; (void)out_size;
    const float* R   = (const float*)d_in[0];
    const float* D   = (const float*)d_in[1];
    const float* T   = (const float*)d_in[2];
    const float* H_d = (const float*)d_in[3];
    const float* H_t = (const float*)d_in[4];
    const float* W1g[2] = {(const float*)d_in[5], (const float*)d_in[7]};
    const float* W2g[2] = {(const float*)d_in[6], (const float*)d_in[8]};
    const float* Wd[3]  = {(const float*)d_in[9],  (const float*)d_in[11], (const float*)d_in[13]};
    const float* Wt[3]  = {(const float*)d_in[10], (const float*)d_in[12], (const float*)d_in[14]};
    float* out = (float*)d_out;

    // padded K extents (multiples of 32)
    const int KpD = 4000, KpT = 2016, KpU = 224;
    const int KpF0 = 256;   // level-0 feature K
    const int Kp3F0 = 768, Kp3F1 = 608;

    char* base = (char*)d_ws;
    size_t off = 0;
    auto alloc = [&](size_t bytes) -> void* {
        off = (off + 255) & ~(size_t)255;
        void* p = base + off;
        off += bytes;
        return p;
    };
    // fp32 scratch
    float* sd   = (float*)alloc(DNUM * 4);
    float* st   = (float*)alloc(TNUM * 4);
    float* rdR  = (float*)alloc(DNUM * 4);
    float* rtR  = (float*)alloc(TNUM * 4);
    float* rdv  = (float*)alloc(DNUM * 4);
    float* rt   = (float*)alloc(TNUM * 4);
    float* hd1  = (float*)alloc((size_t)DNUM * UNITS * 4);
    float* ht1  = (float*)alloc((size_t)TNUM * UNITS * 4);
    float* hd2  = (float*)alloc((size_t)DNUM * UNITS * 4);
    float* ht2  = (float*)alloc((size_t)TNUM * UNITS * 4);
    float* GHd  = (float*)alloc((size_t)DNUM * UNITS * 4);
    float* GHt  = (float*)alloc((size_t)TNUM * UNITS * 4);
    float* tv   = (float*)alloc((size_t)DNUM * TOPK * 4);
    int*   ti   = (int*)alloc((size_t)DNUM * TOPK * 4);
    float* accT = (float*)alloc((size_t)TNUM * FEAT * 4);
    float* Cd   = (float*)alloc((size_t)DNUM * 3 * FEAT * 4);
    float* Ct   = (float*)alloc((size_t)TNUM * 3 * FEAT * 4);
    float* Cpart = (float*)alloc((size_t)8600000 * 4);
    // bf16 packs
    unsigned short* Dp   = (unsigned short*)alloc((size_t)4096 * 12000 * 2);
    unsigned short* Tp   = (unsigned short*)alloc((size_t)2048 * 6048 * 2);
    unsigned short* Rnp  = (unsigned short*)alloc((size_t)4096 * 4032 * 2);
    unsigned short* RnTp = (unsigned short*)alloc((size_t)2048 * 8000 * 2);
    unsigned short* hdAp = (unsigned short*)alloc((size_t)4096 * 768 * 2);
    unsigned short* htAp = (unsigned short*)alloc((size_t)2048 * 768 * 2);
    unsigned short* hdTp = (unsigned short*)alloc((size_t)256 * 12000 * 2);
    unsigned short* htTp = (unsigned short*)alloc((size_t)256 * 6048 * 2);
    unsigned short* GHdp = (unsigned short*)alloc((size_t)4096 * 672 * 2);
    unsigned short* GHtp = (unsigned short*)alloc((size_t)2048 * 672 * 2);
    unsigned short* CdAp = (unsigned short*)alloc((size_t)4096 * 2304 * 2);
    unsigned short* CtAp = (unsigned short*)alloc((size_t)2048 * 2304 * 2);
    unsigned short* W1p  = (unsigned short*)alloc((size_t)256 * 768 * 2);
    unsigned short* W2p  = (unsigned short*)alloc((size_t)256 * 768 * 2);
    unsigned short* WdP  = (unsigned short*)alloc((size_t)256 * 2304 * 2);
    unsigned short* WtP  = (unsigned short*)alloc((size_t)256 * 2304 * 2);
    size_t need = off;

    if (ws_size < need) {  // not enough workspace for packs -> proven fp32 path
        run_fp32_path(d_in, d_out, d_ws, stream);
        return;
    }

    // ---- norms ----
    rowsum_rsqrt_k<<<DNUM, 256, 0, stream>>>(D, DNUM, sd);
    rowsum_rsqrt_k<<<TNUM, 256, 0, stream>>>(T, TNUM, st);
    rowsum_rsqrt_k<<<DNUM, 256, 0, stream>>>(R, TNUM, rdR);
    fill_zero_k<<<cdiv(TNUM, 256), 256, 0, stream>>>(rtR, TNUM);
    colsum_partial_k<<<dim3(cdiv(TNUM, 256), 32), 256, 0, stream>>>(R, DNUM, TNUM, rtR);
    rsqrt_safe_k<<<cdiv(TNUM, 256), 256, 0, stream>>>(rtR, TNUM);

    // ---- static packs (norms folded) ----
    pack_rows_k<<<4096, 256, 0, stream>>>(D, DNUM, DNUM, KpD, 3, 3 * KpD, sd, sd, Dp);
    pack_rows_k<<<2048, 256, 0, stream>>>(T, TNUM, TNUM, KpT, 3, 3 * KpT, st, st, Tp);
    pack_rows_k<<<4096, 256, 0, stream>>>(R, DNUM, TNUM, KpT, 2, 2 * KpT, rdR, rtR, Rnp);
    pack_trans_k<<<dim3(2048 / 32, KpD / 32), 256, 0, stream>>>(R, DNUM, TNUM, KpD, 2, 2 * KpD, rdR, rtR, RnTp);

    const float* hd_in = H_d;
    const float* ht_in = H_t;
    for (int l = 0; l < 2; ++l) {
        int F = (l == 0) ? FEAT : UNITS;
        int KpF = (l == 0) ? KpF0 : KpU;
        int Kp3 = (l == 0) ? Kp3F0 : Kp3F1;
        int ld3 = 3 * F;
        // GL scoring path (x3 splits: fp32-accurate, keeps top-k stable)
        pack_rows_k<<<4096, 256, 0, stream>>>(hd_in, DNUM, F, KpF, 3, 3 * KpF, nullptr, nullptr, hdAp);
        pack_rows_k<<<2048, 256, 0, stream>>>(ht_in, TNUM, F, KpF, 3, 3 * KpF, nullptr, nullptr, htAp);
        pack_trans_k<<<dim3(8, KpF / 32), 256, 0, stream>>>(W1g[l], F, UNITS, KpF, 3, 3 * KpF, nullptr, nullptr, W1p);
        pack_trans_k<<<dim3(8, KpF / 32), 256, 0, stream>>>(W2g[l], F, UNITS, KpF, 3, 3 * KpF, nullptr, nullptr, W2p);
        mm<3, ENONE>(stream, hdAp, 3 * KpF, W1p, 3 * KpF, KpF, DNUM, UNITS, 2, Cpart, nullptr, 0, 0);
        epi<ENONE>(stream, Cpart, 2, DNUM, UNITS, GHd, UNITS, 0);
        mm<3, ENONE>(stream, htAp, 3 * KpF, W2p, 3 * KpF, KpF, TNUM, UNITS, 2, Cpart, nullptr, 0, 0);
        epi<ENONE>(stream, Cpart, 2, TNUM, UNITS, GHt, UNITS, 0);
        pack_rows_k<<<4096, 256, 0, stream>>>(GHd, DNUM, UNITS, KpU, 3, 3 * KpU, nullptr, nullptr, GHdp);
        pack_rows_k<<<2048, 256, 0, stream>>>(GHt, TNUM, UNITS, KpU, 3, 3 * KpU, nullptr, nullptr, GHtp);
        mm<3, ESIG>(stream, GHdp, 3 * KpU, GHtp, 3 * KpU, KpU, DNUM, TNUM, 1, Cpart, out, TNUM, 0);
        // top-k + sparse CGC terms
        topk_k<<<DNUM, 256, 0, stream>>>(out, TNUM, tv, ti, rdv);
        fill_zero_k<<<cdiv(TNUM, 256), 256, 0, stream>>>(rt, TNUM);
        scatter_colsum_k<<<cdiv(DNUM * TOPK, 256), 256, 0, stream>>>(tv, ti, rt, DNUM * TOPK);
        rsqrt_safe_k<<<cdiv(TNUM, 256), 256, 0, stream>>>(rt, TNUM);
        gather_hdt_k<<<DNUM, 256, 0, stream>>>(tv, ti, rt, rdv, ht_in, F, Cd, ld3, F);
        fill_zero_k<<<cdiv(TNUM * F, 256), 256, 0, stream>>>(accT, TNUM * F);
        scatter_htd_k<<<DNUM, 256, 0, stream>>>(tv, ti, rdv, hd_in, F, accT);
        finalize_htd_k<<<TNUM, 256, 0, stream>>>(accT, rt, F, Ct, ld3, F);
        copy_rows_k<<<DNUM, 256, 0, stream>>>(hd_in, F, Cd, ld3);
        copy_rows_k<<<TNUM, 256, 0, stream>>>(ht_in, F, Ct, ld3);
        // dense graph convs (norms folded into Dp/Tp)
        pack_trans_k<<<dim3(8, KpD / 32), 256, 0, stream>>>(hd_in, DNUM, F, KpD, 3, 3 * KpD, nullptr, nullptr, hdTp);
        mm<3, ENONE>(stream, Dp, 3 * KpD, hdTp, 3 * KpD, KpD, DNUM, F, 8, Cpart, nullptr, 0, 0);
        epi<ERELU>(stream, Cpart, 8, DNUM, F, Cd, ld3, 2 * F);
        pack_trans_k<<<dim3(8, KpT / 32), 256, 0, stream>>>(ht_in, TNUM, F, KpT, 3, 3 * KpT, nullptr, nullptr, htTp);
        mm<3, ENONE>(stream, Tp, 3 * KpT, htTp, 3 * KpT, KpT, TNUM, F, 8, Cpart, nullptr, 0, 0);
        epi<ERELU>(stream, Cpart, 8, TNUM, F, Ct, ld3, 2 * F);
        // dense output projection
        pack_rows_k<<<4096, 256, 0, stream>>>(Cd, DNUM, 3 * F, Kp3, 3, 3 * Kp3, nullptr, nullptr, CdAp);
        pack_rows_k<<<2048, 256, 0, stream>>>(Ct, TNUM, 3 * F, Kp3, 3, 3 * Kp3, nullptr, nullptr, CtAp);
        pack_trans_k<<<dim3(8, Kp3 / 32), 256, 0, stream>>>(Wd[l], 3 * F, UNITS, Kp3, 3, 3 * Kp3, nullptr, nullptr, WdP);
        pack_trans_k<<<dim3(8, Kp3 / 32), 256, 0, stream>>>(Wt[l], 3 * F, UNITS, Kp3, 3, 3 * Kp3, nullptr, nullptr, WtP);
        float* hdo = (l == 0) ? hd1 : hd2;
        float* hto = (l == 0) ? ht1 : ht2;
        mm<3, ENONE>(stream, CdAp, 3 * Kp3, WdP, 3 * Kp3, Kp3, DNUM, UNITS, 4, Cpart, nullptr, 0, 0);
        epi<ERELU>(stream, Cpart, 4, DNUM, UNITS, hdo, UNITS, 0);
        mm<3, ENONE>(stream, CtAp, 3 * Kp3, WtP, 3 * Kp3, Kp3, TNUM, UNITS, 4, Cpart, nullptr, 0, 0);
        epi<ERELU>(stream, Cpart, 4, TNUM, UNITS, hto, UNITS, 0);
        hd_in = hdo;
        ht_in = hto;
    }

    // ---- output CGC on original dense graphs (x2 splits suffice downstream of top-k) ----
    {
        int F = UNITS, ld3 = 3 * UNITS, Kp3 = Kp3F1;
        pack_trans_k<<<dim3(8, KpT / 32), 256, 0, stream>>>(ht_in, TNUM, F, KpT, 2, 3 * KpT, nullptr, nullptr, htTp);
        mm<2, ENONE>(stream, Rnp, 2 * KpT, htTp, 3 * KpT, KpT, DNUM, F, 8, Cpart, nullptr, 0, 0);
        epi<ERELU>(stream, Cpart, 8, DNUM, F, Cd, ld3, F);
        pack_trans_k<<<dim3(8, KpD / 32), 256, 0, stream>>>(hd_in, DNUM, F, KpD, 2, 3 * KpD, nullptr, nullptr, hdTp);
        mm<2, ENONE>(stream, RnTp, 2 * KpD, hdTp, 3 * KpD, KpD, TNUM, F, 16, Cpart, nullptr, 0, 0);
        epi<ERELU>(stream, Cpart, 16, TNUM, F, Ct, ld3, F);
        copy_rows_k<<<DNUM, 256, 0, stream>>>(hd_in, F, Cd, ld3);
        copy_rows_k<<<TNUM, 256, 0, stream>>>(ht_in, F, Ct, ld3);
        mm<2, ENONE>(stream, Dp, 3 * KpD, hdTp, 3 * KpD, KpD, DNUM, F, 8, Cpart, nullptr, 0, 0);
        epi<ERELU>(stream, Cpart, 8, DNUM, F, Cd, ld3, 2 * F);
        mm<2, ENONE>(stream, Tp, 3 * KpT, htTp, 3 * KpT, KpT, TNUM, F, 8, Cpart, nullptr, 0, 0);
        epi<ERELU>(stream, Cpart, 8, TNUM, F, Ct, ld3, 2 * F);
        pack_rows_k<<<4096, 256, 0, stream>>>(Cd, DNUM, 3 * F, Kp3, 2, 3 * Kp3, nullptr, nullptr, CdAp);
        pack_rows_k<<<2048, 256, 0, stream>>>(Ct, TNUM, 3 * F, Kp3, 2, 3 * Kp3, nullptr, nullptr, CtAp);
        pack_trans_k<<<dim3(8, Kp3 / 32), 256, 0, stream>>>(Wd[2], 3 * F, UNITS, Kp3, 2, 3 * Kp3, nullptr, nullptr, WdP);
        pack_trans_k<<<dim3(8, Kp3 / 32), 256, 0, stream>>>(Wt[2], 3 * F, UNITS, Kp3, 2, 3 * Kp3, nullptr, nullptr, WtP);
        mm<2, ENONE>(stream, CdAp, 3 * Kp3, WdP, 3 * Kp3, Kp3, DNUM, UNITS, 4, Cpart, nullptr, 0, 0);
        epi<ERELU>(stream, Cpart, 4, DNUM, UNITS, hd1, UNITS, 0);
        mm<2, ENONE>(stream, CtAp, 3 * Kp3, WtP, 3 * Kp3, Kp3, TNUM, UNITS, 4, Cpart, nullptr, 0, 0);
        epi<ERELU>(stream, Cpart, 4, TNUM, UNITS, ht1, UNITS, 0);
        // R_pred = sigmoid(hd1 @ ht1^T)
        pack_rows_k<<<4096, 256, 0, stream>>>(hd1, DNUM, UNITS, KpU, 2, 3 * KpU, nullptr, nullptr, GHdp);
        pack_rows_k<<<2048, 256, 0, stream>>>(ht1, TNUM, UNITS, KpU, 2, 3 * KpU, nullptr, nullptr, GHtp);
        mm<2, ESIG>(stream, GHdp, 3 * KpU, GHtp, 3 * KpU, KpU, DNUM, TNUM, 1, Cpart, out, TNUM, 0);
    }
}

// Round 3
// 1550.105 us; speedup vs baseline: 3.4234x; 3.4105x over previous
//
#include <hip/hip_runtime.h>
#include <math.h>

#define DNUM 4000
#define TNUM 2000
#define FEAT 256
#define UNITS 200
#define TOPK 10

typedef __attribute__((ext_vector_type(8))) short short8;
typedef __attribute__((ext_vector_type(4))) float f32x4;

enum { ENONE = 0, ERELU = 1, ERELUSC = 2, ESIG = 3 };

typedef unsigned int u32_g __attribute__((address_space(1)));
typedef unsigned int u32_l __attribute__((address_space(3)));

__device__ __forceinline__ unsigned short f2bf(float x) {
    union { float f; unsigned u; } v; v.f = x;
    unsigned r = v.u + 0x7fffu + ((v.u >> 16) & 1u);  // RNE
    return (unsigned short)(r >> 16);
}
__device__ __forceinline__ float bf2f(unsigned short b) {
    union { float f; unsigned u; } v; v.u = ((unsigned)b) << 16; return v.f;
}
__device__ __forceinline__ void ld_lds16(const void* g, void* l) {
    __builtin_amdgcn_global_load_lds((const u32_g*)g, (u32_l*)l, 16, 0, 0);
}

static inline int cdiv(int a, int b) { return (a + b - 1) / b; }

// ---------------- small utility kernels ----------------

__global__ void fill_zero_k(float* __restrict__ p, int n) {
    int i = blockIdx.x * 256 + threadIdx.x;
    if (i < n) p[i] = 0.f;
}

__global__ void rowsum_rsqrt_k(const float* __restrict__ A, int cols, float* __restrict__ out) {
    int r = blockIdx.x;
    int tid = threadIdx.x;
    const float* row = A + (size_t)r * cols;
    float s = 0.f;
    for (int j = tid; j < cols; j += 256) s += row[j];
    __shared__ float red[256];
    red[tid] = s;
    __syncthreads();
    for (int st = 128; st > 0; st >>= 1) {
        if (tid < st) red[tid] += red[tid + st];
        __syncthreads();
    }
    if (tid == 0) {
        float n = red[0];
        out[r] = (n == 0.f) ? 1.f : (1.f / sqrtf(n));
    }
}

__global__ void colsum_partial_k(const float* __restrict__ A, int rows, int cols,
                                 float* __restrict__ out) {
    int j = blockIdx.x * 256 + threadIdx.x;
    if (j >= cols) return;
    int chunk = blockIdx.y, nch = gridDim.y;
    int r0 = (int)((long long)rows * chunk / nch);
    int r1 = (int)((long long)rows * (chunk + 1) / nch);
    float s = 0.f;
    for (int i = r0; i < r1; i++) s += A[(size_t)i * cols + j];
    atomicAdd(&out[j], s);
}

__global__ void rsqrt_safe_k(float* __restrict__ v, int n) {
    int i = blockIdx.x * 256 + threadIdx.x;
    if (i < n) {
        float x = v[i];
        v[i] = (x == 0.f) ? 1.f : (1.f / sqrtf(x));
    }
}

__global__ void copy_rows_k(const float* __restrict__ src, int F,
                            float* __restrict__ dst, int ldc) {
    int i = blockIdx.x;
    for (int f = threadIdx.x; f < F; f += 256)
        dst[(size_t)i * ldc + f] = src[(size_t)i * F + f];
}

// ---------------- top-k ----------------
__global__ void topk_k(const float* __restrict__ S, int cols,
                       float* __restrict__ tv, int* __restrict__ ti,
                       float* __restrict__ rd) {
    int row = blockIdx.x;
    int tid = threadIdx.x;
    const float* srow = S + (size_t)row * cols;
    __shared__ float vals[2048];
    __shared__ float redv[256];
    __shared__ int   redi[256];
    __shared__ float selv[TOPK];
    __shared__ int   seli[TOPK];
    for (int j = tid; j < cols; j += 256) vals[j] = srow[j];
    __syncthreads();
    for (int it = 0; it < TOPK; ++it) {
        float bv = -3.0e38f;
        int bi = 0x7fffffff;
        for (int j = tid; j < cols; j += 256) {
            float v = vals[j];
            if (v > bv || (v == bv && j < bi)) { bv = v; bi = j; }
        }
        redv[tid] = bv; redi[tid] = bi;
        __syncthreads();
        for (int st = 128; st > 0; st >>= 1) {
            if (tid < st) {
                float v2 = redv[tid + st]; int i2 = redi[tid + st];
                if (v2 > redv[tid] || (v2 == redv[tid] && i2 < redi[tid])) {
                    redv[tid] = v2; redi[tid] = i2;
                }
            }
            __syncthreads();
        }
        if (tid == 0) {
            selv[it] = redv[0];
            seli[it] = redi[0];
            vals[redi[0]] = -3.0e38f;
        }
        __syncthreads();
    }
    if (tid < TOPK) {
        tv[(size_t)row * TOPK + tid] = selv[tid];
        ti[(size_t)row * TOPK + tid] = seli[tid];
    }
    if (tid == 0) {
        float s = 0.f;
        for (int m = 0; m < TOPK; m++) s += selv[m];
        rd[row] = (s == 0.f) ? 1.f : (1.f / sqrtf(s));
    }
}

__global__ void scatter_colsum_k(const float* __restrict__ tv, const int* __restrict__ ti,
                                 float* __restrict__ nt, int n) {
    int g = blockIdx.x * 256 + threadIdx.x;
    if (g < n) atomicAdd(&nt[ti[g]], tv[g]);
}

__global__ void gather_hdt_k(const float* __restrict__ tv, const int* __restrict__ ti,
                             const float* __restrict__ rt, const float* __restrict__ rd,
                             const float* __restrict__ ht, int F,
                             float* __restrict__ C, int ldc, int coloff) {
    int i = blockIdx.x;
    int tid = threadIdx.x;
    __shared__ float w[TOPK];
    __shared__ int   id[TOPK];
    if (tid < TOPK) {
        int idx = ti[(size_t)i * TOPK + tid];
        id[tid] = idx;
        w[tid] = tv[(size_t)i * TOPK + tid] * rt[idx];
    }
    __syncthreads();
    float s = rd[i];
    for (int f = tid; f < F; f += 256) {
        float acc = 0.f;
#pragma unroll
        for (int m = 0; m < TOPK; ++m)
            acc += w[m] * ht[(size_t)id[m] * F + f];
        C[(size_t)i * ldc + coloff + f] = fmaxf(s * acc, 0.f);
    }
}

__global__ void scatter_htd_k(const float* __restrict__ tv, const int* __restrict__ ti,
                              const float* __restrict__ rd, const float* __restrict__ hd,
                              int F, float* __restrict__ accT) {
    int i = blockIdx.x;
    int tid = threadIdx.x;
    __shared__ float row[256];
    __shared__ float w[TOPK];
    __shared__ int   id[TOPK];
    for (int f = tid; f < F; f += 256) row[f] = hd[(size_t)i * F + f];
    if (tid < TOPK) {
        id[tid] = ti[(size_t)i * TOPK + tid];
        w[tid] = tv[(size_t)i * TOPK + tid] * rd[i];
    }
    __syncthreads();
    for (int m = 0; m < TOPK; ++m) {
        float wm = w[m];
        int j = id[m];
        for (int f = tid; f < F; f += 256)
            atomicAdd(&accT[(size_t)j * F + f], wm * row[f]);
    }
}

__global__ void finalize_htd_k(const float* __restrict__ accT, const float* __restrict__ rt,
                               int F, float* __restrict__ C, int ldc, int coloff) {
    int j = blockIdx.x;
    float s = rt[j];
    for (int f = threadIdx.x; f < F; f += 256)
        C[(size_t)j * ldc + coloff + f] = fmaxf(s * accT[(size_t)j * F + f], 0.f);
}

// ---------------- bf16-split pack kernels (chunk-aware) ----------------
// Pack rows [r0, r0+grid) of X[Rtot,C] (times rs[r]*cs[c]) into out rows [0,grid),
// NS bf16 split segments at col offsets s*Kp, zero-padded.
__global__ void pack_rows_k(const float* __restrict__ X, int Rtot, int C, int r0,
                            int Kp, int NS, int ld,
                            const float* __restrict__ rs, const float* __restrict__ cs,
                            unsigned short* __restrict__ out) {
    int l = blockIdx.x;
    int r = r0 + l;
    unsigned short* orow = out + (size_t)l * ld;
    if (r >= Rtot) {
        for (int c = threadIdx.x; c < NS * Kp; c += 256) orow[c] = 0;
        return;
    }
    float rsc = rs ? rs[r] : 1.f;
    const float* xrow = X + (size_t)r * C;
    for (int c = threadIdx.x; c < Kp; c += 256) {
        float v = 0.f;
        if (c < C) { v = xrow[c] * rsc; if (cs) v *= cs[c]; }
        unsigned short b0 = f2bf(v);
        orow[c] = b0;
        if (NS >= 2) {
            float r1 = v - bf2f(b0);
            unsigned short b1 = f2bf(r1);
            orow[Kp + c] = b1;
            if (NS == 3) orow[2 * Kp + c] = f2bf(r1 - bf2f(b1));
        }
    }
}

// Transposed pack: out[local_col][s*Kp + k] = split(X[k][c0base+local_col]*ks[k]*ns[c]);
// grid (cols_alloc/32, Kp/32)
__global__ void pack_trans_k(const float* __restrict__ X, int Kact, int Ctot, int c0base,
                             int Kp, int NS, int ld,
                             const float* __restrict__ ks, const float* __restrict__ ns,
                             unsigned short* __restrict__ out) {
    __shared__ float tile[32][33];
    int c0 = blockIdx.x * 32, k0 = blockIdx.y * 32;
    int ci = threadIdx.x & 31, kq = threadIdx.x >> 5;
    for (int i = 0; i < 4; ++i) {
        int k = k0 + kq * 4 + i;
        int cg = c0base + c0 + ci;
        float v = 0.f;
        if (k < Kact && cg < Ctot) {
            v = X[(size_t)k * Ctot + cg];
            if (ks) v *= ks[k];
            if (ns) v *= ns[cg];
        }
        tile[kq * 4 + i][ci] = v;
    }
    __syncthreads();
    int ko = threadIdx.x & 31, cq = threadIdx.x >> 5;
    for (int i = 0; i < 4; ++i) {
        int c = cq * 4 + i;
        float v = tile[ko][c];
        unsigned short b0 = f2bf(v);
        unsigned short* o = out + (size_t)(c0 + c) * ld + (k0 + ko);
        o[0] = b0;
        if (NS >= 2) {
            float r1 = v - bf2f(b0);
            unsigned short b1 = f2bf(r1);
            o[Kp] = b1;
            if (NS == 3) o[2 * Kp] = f2bf(r1 - bf2f(b1));
        }
    }
}

// ---------------- MFMA split-GEMM ----------------
// A [.., ldA] bf16 (K-contig, split segs at s*Kp), B [.., ldB] in B^T layout.
// C = sum_{i+j<MAXS} Ai Bj^T over logical K = Kp (ktot = Kp/32 K-tiles).
// grid (Nt, Mt, splits); splits>1 -> raw partials Cpart[z][M][N]; else epilogue into dst.
template <int MAXS, int EPI>
__global__ __launch_bounds__(256) void gemm_bt_k(
    const unsigned short* __restrict__ A, int ldA,
    const unsigned short* __restrict__ B, int ldB,
    int Kp, int ktot, int splits,
    float* __restrict__ Cpart,
    float* __restrict__ dst, int ldc, int coloff,
    int M, int N) {
    __shared__ __align__(16) short As[MAXS][128 * 32];
    __shared__ __align__(16) short Bs[MAXS][128 * 32];
    int tid = threadIdx.x;
    int lane = tid & 63, wid = tid >> 6;
    int wm = wid >> 1, wn = wid & 1;
    int bm = blockIdx.y * 128, bn = blockIdx.x * 128;
    int z = blockIdx.z;
    int kt0 = (int)((long long)ktot * z / splits);
    int kt1 = (int)((long long)ktot * (z + 1) / splits);
    int r_i = lane & 15, quad = lane >> 4;
    f32x4 acc[4][4] = {};
    for (int t = kt0; t < kt1; ++t) {
        int kbase = t * 32;
#pragma unroll
        for (int s = 0; s < MAXS; ++s) {
#pragma unroll
            for (int it = 0; it < 2; ++it) {
                int flat = (it * 256 + tid) * 8;
                int row = flat >> 5;
                int ko = flat & 31;
                ld_lds16(A + (size_t)(bm + row) * ldA + s * Kp + kbase + ko, &As[s][flat]);
                ld_lds16(B + (size_t)(bn + row) * ldB + s * Kp + kbase + ko, &Bs[s][flat]);
            }
        }
        __syncthreads();
        short8 af[MAXS][4], bfr[MAXS][4];
#pragma unroll
        for (int s = 0; s < MAXS; ++s)
#pragma unroll
            for (int mi = 0; mi < 4; ++mi) {
                af[s][mi]  = *(const short8*)&As[s][(wm * 64 + mi * 16 + r_i) * 32 + quad * 8];
                bfr[s][mi] = *(const short8*)&Bs[s][(wn * 64 + mi * 16 + r_i) * 32 + quad * 8];
            }
#pragma unroll
        for (int i = 0; i < MAXS; ++i)
#pragma unroll
            for (int j = 0; j < MAXS; ++j) {
                if (i + j >= MAXS) continue;
#pragma unroll
                for (int mi = 0; mi < 4; ++mi)
#pragma unroll
                    for (int ni = 0; ni < 4; ++ni)
                        acc[mi][ni] = __builtin_amdgcn_mfma_f32_16x16x32_bf16(
                            af[i][mi], bfr[j][ni], acc[mi][ni], 0, 0, 0);
            }
        __syncthreads();
    }
#pragma unroll
    for (int mi = 0; mi < 4; ++mi)
#pragma unroll
        for (int ni = 0; ni < 4; ++ni)
#pragma unroll
            for (int r = 0; r < 4; ++r) {
                int gm = bm + wm * 64 + mi * 16 + quad * 4 + r;
                int gn = bn + wn * 64 + ni * 16 + r_i;
                if (gm >= M || gn >= N) continue;
                float v = acc[mi][ni][r];
                if (splits > 1) {
                    Cpart[((size_t)z * M + gm) * N + gn] = v;
                } else {
                    if (EPI == ERELU) v = fmaxf(v, 0.f);
                    else if (EPI == ESIG) v = 1.f / (1.f + expf(-v));
                    dst[(size_t)gm * ldc + coloff + gn] = v;
                }
            }
}

template <int EPI>
__global__ void epi_k(const float* __restrict__ Cpart, int splits, int M, int N,
                      float* __restrict__ dst, int ldc, int coloff) {
    int idx = blockIdx.x * 256 + threadIdx.x;
    if (idx >= M * N) return;
    size_t stride = (size_t)M * N;
    float v = 0.f;
    for (int s = 0; s < splits; ++s) v += Cpart[s * stride + idx];
    int m = idx / N, n = idx - m * N;
    if (EPI == ERELU) v = fmaxf(v, 0.f);
    else if (EPI == ESIG) v = 1.f / (1.f + expf(-v));
    dst[(size_t)m * ldc + coloff + n] = v;
}

// ---------------- host-side chunked GEMM helpers ----------------
#define CPN (4 * 1024 * 1024)  // Cpart capacity in floats (16.8 MB)

template <int MAXS, int EPI>
static void gemm_rowsA(hipStream_t s,
                       const float* Asrc, int Mtot, int Kact, int Kp,
                       const float* rsc, const float* csc,
                       unsigned short* PA, size_t PAelems,
                       const unsigned short* Bp, int ldB, int N,
                       float* Cpart, float* dst, int ldc, int coloff) {
    int ldA = MAXS * Kp;
    int maxCM = (int)((PAelems / (size_t)ldA) / 128) * 128;
    if (maxCM < 128) maxCM = 128;
    int ktiles = Kp / 32;
    for (int r0 = 0; r0 < Mtot; r0 += maxCM) {
        int Mv = (Mtot - r0 < maxCM) ? (Mtot - r0) : maxCM;
        int Ma = cdiv(Mv, 128) * 128;
        pack_rows_k<<<Ma, 256, 0, s>>>(Asrc, Mtot, Kact, r0, Kp, MAXS, ldA, rsc, csc, PA);
        int splits = CPN / (Ma * N);
        if (splits < 1) splits = 1;
        if (splits > 16) splits = 16;
        if (splits > ktiles) splits = ktiles;
        dim3 g(cdiv(N, 128), Ma / 128, splits);
        if (splits == 1) {
            gemm_bt_k<MAXS, EPI><<<g, 256, 0, s>>>(PA, ldA, Bp, ldB, Kp, ktiles, 1, nullptr,
                                                   dst + (size_t)r0 * ldc, ldc, coloff, Mv, N);
        } else {
            gemm_bt_k<MAXS, EPI><<<g, 256, 0, s>>>(PA, ldA, Bp, ldB, Kp, ktiles, splits, Cpart,
                                                   nullptr, 0, 0, Mv, N);
            epi_k<EPI><<<cdiv(Mv * N, 256), 256, 0, s>>>(Cpart, splits, Mv, N,
                                                         dst + (size_t)r0 * ldc, ldc, coloff);
        }
    }
}

template <int MAXS, int EPI>
static void gemm_transA(hipStream_t s,
                        const float* Asrc, int Mtot, int Kact, int Kp,
                        const float* ks, const float* ns,
                        unsigned short* PA, size_t PAelems,
                        const unsigned short* Bp, int ldB, int N,
                        float* Cpart, float* dst, int ldc, int coloff) {
    int ldA = MAXS * Kp;
    int maxCM = (int)((PAelems / (size_t)ldA) / 128) * 128;
    if (maxCM < 128) maxCM = 128;
    int ktiles = Kp / 32;
    for (int r0 = 0; r0 < Mtot; r0 += maxCM) {
        int Mv = (Mtot - r0 < maxCM) ? (Mtot - r0) : maxCM;
        int Ma = cdiv(Mv, 128) * 128;
        pack_trans_k<<<dim3(Ma / 32, ktiles), 256, 0, s>>>(Asrc, Kact, Mtot, r0, Kp, MAXS, ldA,
                                                           ks, ns, PA);
        int splits = CPN / (Ma * N);
        if (splits < 1) splits = 1;
        if (splits > 16) splits = 16;
        if (splits > ktiles) splits = ktiles;
        dim3 g(cdiv(N, 128), Ma / 128, splits);
        if (splits == 1) {
            gemm_bt_k<MAXS, EPI><<<g, 256, 0, s>>>(PA, ldA, Bp, ldB, Kp, ktiles, 1, nullptr,
                                                   dst + (size_t)r0 * ldc, ldc, coloff, Mv, N);
        } else {
            gemm_bt_k<MAXS, EPI><<<g, 256, 0, s>>>(PA, ldA, Bp, ldB, Kp, ktiles, splits, Cpart,
                                                   nullptr, 0, 0, Mv, N);
            epi_k<EPI><<<cdiv(Mv * N, 256), 256, 0, s>>>(Cpart, splits, Mv, N,
                                                         dst + (size_t)r0 * ldc, ldc, coloff);
        }
    }
}

// ---------------- fallback fp32 SGEMM (round-1 proven path) ----------------
#define BM 64
#define BN 64
#define BK 16

template <bool TA, bool TB, int EPI>
__global__ __launch_bounds__(256) void gemm_f32_k(
    int M, int N, int K,
    const float* __restrict__ A, int lda,
    const float* __restrict__ B, int ldb,
    float* __restrict__ C, int ldc,
    const float* __restrict__ scaleB,
    const float* __restrict__ scaleC) {
    __shared__ float Asf[BK][BM + 4];
    __shared__ float Bsf[BK][BN + 4];
    int bn = blockIdx.x * BN;
    int bm = blockIdx.y * BM;
    int tid = threadIdx.x;
    int tx = tid & 15;
    int ty = tid >> 4;
    float acc[4][4] = {};
    for (int t = 0; t < K; t += BK) {
#pragma unroll
        for (int it = 0; it < (BM * BK) / 256; ++it) {
            int l = tid + it * 256;
            int k, m;
            if (TA) { k = l / BM; m = l % BM; }
            else    { m = l / BK; k = l % BK; }
            int gm = bm + m, gk = t + k;
            float v = 0.f;
            if (gm < M && gk < K)
                v = TA ? A[(size_t)gk * lda + gm] : A[(size_t)gm * lda + gk];
            Asf[k][m] = v;
        }
#pragma unroll
        for (int it = 0; it < (BN * BK) / 256; ++it) {
            int l = tid + it * 256;
            int k, n;
            if (TB) { n = l / BK; k = l % BK; }
            else    { k = l / BN; n = l % BN; }
            int gn = bn + n, gk = t + k;
            float v = 0.f;
            if (gn < N && gk < K) {
                v = TB ? B[(size_t)gn * ldb + gk] : B[(size_t)gk * ldb + gn];
                if (scaleB) v *= scaleB[gk];
            }
            Bsf[k][n] = v;
        }
        __syncthreads();
#pragma unroll
        for (int kk = 0; kk < BK; ++kk) {
            float a[4], b[4];
#pragma unroll
            for (int i = 0; i < 4; ++i) a[i] = Asf[kk][ty * 4 + i];
#pragma unroll
            for (int j = 0; j < 4; ++j) b[j] = Bsf[kk][tx * 4 + j];
#pragma unroll
            for (int i = 0; i < 4; ++i)
#pragma unroll
                for (int j = 0; j < 4; ++j)
                    acc[i][j] = fmaf(a[i], b[j], acc[i][j]);
        }
        __syncthreads();
    }
#pragma unroll
    for (int i = 0; i < 4; ++i) {
        int gm = bm + ty * 4 + i;
        if (gm >= M) continue;
#pragma unroll
        for (int j = 0; j < 4; ++j) {
            int gn = bn + tx * 4 + j;
            if (gn >= N) continue;
            float v = acc[i][j];
            if (EPI == ERELUSC) v = fmaxf(scaleC[gm] * v, 0.f);
            else if (EPI == ERELU) v = fmaxf(v, 0.f);
            else if (EPI == ESIG) v = 1.f / (1.f + expf(-v));
            C[(size_t)gm * ldc + gn] = v;
        }
    }
}

template <bool TA, bool TB, int EPI>
static inline void launch_gemm_f32(int M, int N, int K,
                                   const float* A, int lda,
                                   const float* B, int ldb,
                                   float* C, int ldc,
                                   const float* sB, const float* sC,
                                   hipStream_t stream) {
    dim3 grid((N + BN - 1) / BN, (M + BM - 1) / BM);
    gemm_f32_k<TA, TB, EPI><<<grid, dim3(256), 0, stream>>>(M, N, K, A, lda, B, ldb, C, ldc, sB, sC);
}

static void run_fp32_path(void* const* d_in, void* d_out, void* d_ws, hipStream_t stream) {
    const float* R   = (const float*)d_in[0];
    const float* D   = (const float*)d_in[1];
    const float* T   = (const float*)d_in[2];
    const float* H_d = (const float*)d_in[3];
    const float* H_t = (const float*)d_in[4];
    const float* W1g[2] = {(const float*)d_in[5], (const float*)d_in[7]};
    const float* W2g[2] = {(const float*)d_in[6], (const float*)d_in[8]};
    const float* Wd[3]  = {(const float*)d_in[9],  (const float*)d_in[11], (const float*)d_in[13]};
    const float* Wt[3]  = {(const float*)d_in[10], (const float*)d_in[12], (const float*)d_in[14]};
    float* out = (float*)d_out;
    float* ws = (float*)d_ws;
    size_t o = 0;
    auto alloc = [&](size_t n) { float* p = ws + o; o += n; return p; };
    float* sd   = alloc(DNUM);
    float* st   = alloc(TNUM);
    float* rdR  = alloc(DNUM);
    float* rtR  = alloc(TNUM);
    float* rd   = alloc(DNUM);
    float* rt   = alloc(TNUM);
    float* hd1  = alloc((size_t)DNUM * UNITS);
    float* ht1  = alloc((size_t)TNUM * UNITS);
    float* hd2  = alloc((size_t)DNUM * UNITS);
    float* ht2  = alloc((size_t)TNUM * UNITS);
    float* GHd  = alloc((size_t)DNUM * UNITS);
    float* GHt  = alloc((size_t)TNUM * UNITS);
    float* tv   = alloc((size_t)DNUM * TOPK);
    int*   ti   = (int*)alloc((size_t)DNUM * TOPK);
    float* accT = alloc((size_t)TNUM * FEAT);
    float* Cd   = alloc((size_t)DNUM * 3 * FEAT);
    float* Ct   = alloc((size_t)TNUM * 3 * FEAT);

    rowsum_rsqrt_k<<<DNUM, 256, 0, stream>>>(D, DNUM, sd);
    rowsum_rsqrt_k<<<TNUM, 256, 0, stream>>>(T, TNUM, st);
    rowsum_rsqrt_k<<<DNUM, 256, 0, stream>>>(R, TNUM, rdR);
    fill_zero_k<<<cdiv(TNUM, 256), 256, 0, stream>>>(rtR, TNUM);
    colsum_partial_k<<<dim3(cdiv(TNUM, 256), 32), 256, 0, stream>>>(R, DNUM, TNUM, rtR);
    rsqrt_safe_k<<<cdiv(TNUM, 256), 256, 0, stream>>>(rtR, TNUM);

    const float* hd_in = H_d;
    const float* ht_in = H_t;
    for (int l = 0; l < 2; ++l) {
        int F = (l == 0) ? FEAT : UNITS;
        int ld3 = 3 * F;
        launch_gemm_f32<false, false, ENONE>(DNUM, UNITS, F, hd_in, F, W1g[l], UNITS, GHd, UNITS, nullptr, nullptr, stream);
        launch_gemm_f32<false, false, ENONE>(TNUM, UNITS, F, ht_in, F, W2g[l], UNITS, GHt, UNITS, nullptr, nullptr, stream);
        launch_gemm_f32<false, true, ESIG>(DNUM, TNUM, UNITS, GHd, UNITS, GHt, UNITS, out, TNUM, nullptr, nullptr, stream);
        topk_k<<<DNUM, 256, 0, stream>>>(out, TNUM, tv, ti, rd);
        fill_zero_k<<<cdiv(TNUM, 256), 256, 0, stream>>>(rt, TNUM);
        scatter_colsum_k<<<cdiv(DNUM * TOPK, 256), 256, 0, stream>>>(tv, ti, rt, DNUM * TOPK);
        rsqrt_safe_k<<<cdiv(TNUM, 256), 256, 0, stream>>>(rt, TNUM);
        gather_hdt_k<<<DNUM, 256, 0, stream>>>(tv, ti, rt, rd, ht_in, F, Cd, ld3, F);
        fill_zero_k<<<cdiv(TNUM * F, 256), 256, 0, stream>>>(accT, TNUM * F);
        scatter_htd_k<<<DNUM, 256, 0, stream>>>(tv, ti, rd, hd_in, F, accT);
        finalize_htd_k<<<TNUM, 256, 0, stream>>>(accT, rt, F, Ct, ld3, F);
        copy_rows_k<<<DNUM, 256, 0, stream>>>(hd_in, F, Cd, ld3);
        copy_rows_k<<<TNUM, 256, 0, stream>>>(ht_in, F, Ct, ld3);
        launch_gemm_f32<false, false, ERELUSC>(DNUM, F, DNUM, D, DNUM, hd_in, F, Cd + 2 * F, ld3, sd, sd, stream);
        launch_gemm_f32<false, false, ERELUSC>(TNUM, F, TNUM, T, TNUM, ht_in, F, Ct + 2 * F, ld3, st, st, stream);
        float* hdo = (l == 0) ? hd1 : hd2;
        float* hto = (l == 0) ? ht1 : ht2;
        launch_gemm_f32<false, false, ERELU>(DNUM, UNITS, 3 * F, Cd, ld3, Wd[l], UNITS, hdo, UNITS, nullptr, nullptr, stream);
        launch_gemm_f32<false, false, ERELU>(TNUM, UNITS, 3 * F, Ct, ld3, Wt[l], UNITS, hto, UNITS, nullptr, nullptr, stream);
        hd_in = hdo;
        ht_in = hto;
    }
    {
        int F = UNITS, ld3 = 3 * UNITS;
        launch_gemm_f32<false, false, ERELUSC>(DNUM, F, TNUM, R, TNUM, ht_in, F, Cd + F, ld3, rtR, rdR, stream);
        launch_gemm_f32<true, false, ERELUSC>(TNUM, F, DNUM, R, TNUM, hd_in, F, Ct + F, ld3, rdR, rtR, stream);
        copy_rows_k<<<DNUM, 256, 0, stream>>>(hd_in, F, Cd, ld3);
        copy_rows_k<<<TNUM, 256, 0, stream>>>(ht_in, F, Ct, ld3);
        launch_gemm_f32<false, false, ERELUSC>(DNUM, F, DNUM, D, DNUM, hd_in, F, Cd + 2 * F, ld3, sd, sd, stream);
        launch_gemm_f32<false, false, ERELUSC>(TNUM, F, TNUM, T, TNUM, ht_in, F, Ct + 2 * F, ld3, st, st, stream);
        launch_gemm_f32<false, false, ERELU>(DNUM, UNITS, 3 * F, Cd, ld3, Wd[2], UNITS, hd1, UNITS, nullptr, nullptr, stream);
        launch_gemm_f32<false, false, ERELU>(TNUM, UNITS, 3 * F, Ct, ld3, Wt[2], UNITS, ht1, UNITS, nullptr, nullptr, stream);
        launch_gemm_f32<false, true, ESIG>(DNUM, TNUM, UNITS, hd1, UNITS, ht1, UNITS, out, TNUM, nullptr, nullptr, stream);
    }
}

// ---------------- main driver ----------------
extern "C" void kernel_launch(void* const* d_in, const int* in_sizes, int n_in,
                              void* d_out, int out_size, void* d_ws, size_t ws_size,
                              hipStream_t stream) {
    (void)in_sizes; (void)n_in; (void)out_size;
    const float* R   = (const float*)d_in[0];
    const float* D   = (const float*)d_in[1];
    const float* T   = (const float*)d_in[2];
    const float* H_d = (const float*)d_in[3];
    const float* H_t = (const float*)d_in[4];
    const float* W1g[2] = {(const float*)d_in[5], (const float*)d_in[7]};
    const float* W2g[2] = {(const float*)d_in[6], (const float*)d_in[8]};
    const float* Wd[3]  = {(const float*)d_in[9],  (const float*)d_in[11], (const float*)d_in[13]};
    const float* Wt[3]  = {(const float*)d_in[10], (const float*)d_in[12], (const float*)d_in[14]};
    float* out = (float*)d_out;   // [4000,2000]; doubles as GL score scratch

    // padded K extents (multiples of 32)
    const int KpD = 4000, KpT = 2016, KpU = 224;
    const int KpF0 = 256;
    const int Kp3F0 = 768, Kp3F1 = 608;

    char* base = (char*)d_ws;
    size_t off = 0;
    auto alloc = [&](size_t bytes) -> void* {
        off = (off + 255) & ~(size_t)255;
        void* p = base + off;
        off += bytes;
        return p;
    };
    float* sd   = (float*)alloc(DNUM * 4);
    float* st   = (float*)alloc(TNUM * 4);
    float* rdR  = (float*)alloc(DNUM * 4);
    float* rtR  = (float*)alloc(TNUM * 4);
    float* rdv  = (float*)alloc(DNUM * 4);
    float* rt   = (float*)alloc(TNUM * 4);
    float* hd1  = (float*)alloc((size_t)DNUM * UNITS * 4);
    float* ht1  = (float*)alloc((size_t)TNUM * UNITS * 4);
    float* hd2  = (float*)alloc((size_t)DNUM * UNITS * 4);
    float* ht2  = (float*)alloc((size_t)TNUM * UNITS * 4);
    float* GHd  = (float*)alloc((size_t)DNUM * UNITS * 4);
    float* GHt  = (float*)alloc((size_t)TNUM * UNITS * 4);
    float* tv   = (float*)alloc((size_t)DNUM * TOPK * 4);
    int*   ti   = (int*)alloc((size_t)DNUM * TOPK * 4);
    float* accT = (float*)alloc((size_t)TNUM * FEAT * 4);
    float* Cd   = (float*)alloc((size_t)DNUM * 3 * FEAT * 4);
    float* Ct   = (float*)alloc((size_t)TNUM * 3 * FEAT * 4);
    float* Cpart = (float*)alloc((size_t)CPN * 4);
    unsigned short* PB = (unsigned short*)alloc((size_t)3200000 * 2);  // B packs (max 3.07M shorts)
    off = (off + 255) & ~(size_t)255;
    // PA = all remaining workspace; need >= 1024 rows x 3 segs x 4000 K x 2B
    const size_t PA_MIN = (size_t)1024 * 3 * 4000 * 2;
    if (ws_size < off + PA_MIN) {   // not enough for the bf16 path
        run_fp32_path(d_in, d_out, d_ws, stream);
        return;
    }
    unsigned short* PA = (unsigned short*)(base + off);
    size_t PAelems = (ws_size - off) / 2;

    // ---- norm vectors ----
    rowsum_rsqrt_k<<<DNUM, 256, 0, stream>>>(D, DNUM, sd);
    rowsum_rsqrt_k<<<TNUM, 256, 0, stream>>>(T, TNUM, st);
    rowsum_rsqrt_k<<<DNUM, 256, 0, stream>>>(R, TNUM, rdR);
    fill_zero_k<<<cdiv(TNUM, 256), 256, 0, stream>>>(rtR, TNUM);
    colsum_partial_k<<<dim3(cdiv(TNUM, 256), 32), 256, 0, stream>>>(R, DNUM, TNUM, rtR);
    rsqrt_safe_k<<<cdiv(TNUM, 256), 256, 0, stream>>>(rtR, TNUM);

    const float* hd_in = H_d;
    const float* ht_in = H_t;
    for (int l = 0; l < 2; ++l) {
        int F = (l == 0) ? FEAT : UNITS;
        int KpF = (l == 0) ? KpF0 : KpU;
        int Kp3 = (l == 0) ? Kp3F0 : Kp3F1;
        int ld3 = 3 * F;
        // ---- GL scoring (3-split, 6 products: fp32-grade, keeps top-k stable) ----
        pack_trans_k<<<dim3(256 / 32, KpF / 32), 256, 0, stream>>>(W1g[l], F, UNITS, 0, KpF, 3, 3 * KpF, nullptr, nullptr, PB);
        gemm_rowsA<3, ENONE>(stream, hd_in, DNUM, F, KpF, nullptr, nullptr, PA, PAelems,
                             PB, 3 * KpF, UNITS, Cpart, GHd, UNITS, 0);
        pack_trans_k<<<dim3(256 / 32, KpF / 32), 256, 0, stream>>>(W2g[l], F, UNITS, 0, KpF, 3, 3 * KpF, nullptr, nullptr, PB);
        gemm_rowsA<3, ENONE>(stream, ht_in, TNUM, F, KpF, nullptr, nullptr, PA, PAelems,
                             PB, 3 * KpF, UNITS, Cpart, GHt, UNITS, 0);
        // bilinear scores -> out (splits forced to 1 by capacity => direct sigmoid)
        pack_rows_k<<<2048, 256, 0, stream>>>(GHt, TNUM, UNITS, 0, KpU, 3, 3 * KpU, nullptr, nullptr, PB);
        gemm_rowsA<3, ESIG>(stream, GHd, DNUM, UNITS, KpU, nullptr, nullptr, PA, PAelems,
                            PB, 3 * KpU, TNUM, Cpart, out, TNUM, 0);
        // ---- top-k + sparse CGC terms ----
        topk_k<<<DNUM, 256, 0, stream>>>(out, TNUM, tv, ti, rdv);
        fill_zero_k<<<cdiv(TNUM, 256), 256, 0, stream>>>(rt, TNUM);
        scatter_colsum_k<<<cdiv(DNUM * TOPK, 256), 256, 0, stream>>>(tv, ti, rt, DNUM * TOPK);
        rsqrt_safe_k<<<cdiv(TNUM, 256), 256, 0, stream>>>(rt, TNUM);
        gather_hdt_k<<<DNUM, 256, 0, stream>>>(tv, ti, rt, rdv, ht_in, F, Cd, ld3, F);
        fill_zero_k<<<cdiv(TNUM * F, 256), 256, 0, stream>>>(accT, TNUM * F);
        scatter_htd_k<<<DNUM, 256, 0, stream>>>(tv, ti, rdv, hd_in, F, accT);
        finalize_htd_k<<<TNUM, 256, 0, stream>>>(accT, rt, F, Ct, ld3, F);
        copy_rows_k<<<DNUM, 256, 0, stream>>>(hd_in, F, Cd, ld3);
        copy_rows_k<<<TNUM, 256, 0, stream>>>(ht_in, F, Ct, ld3);
        // ---- dense graph convs (norms folded into the D/T packs) ----
        // level 0 feeds level-1 top-k => 3-split; level 1 only feeds output => 2-split
        if (l == 0) {
            pack_trans_k<<<dim3(256 / 32, KpD / 32), 256, 0, stream>>>(hd_in, DNUM, F, 0, KpD, 3, 3 * KpD, nullptr, nullptr, PB);
            gemm_rowsA<3, ERELU>(stream, D, DNUM, DNUM, KpD, sd, sd, PA, PAelems,
                                 PB, 3 * KpD, F, Cpart, Cd, ld3, 2 * F);
            pack_trans_k<<<dim3(256 / 32, KpT / 32), 256, 0, stream>>>(ht_in, TNUM, F, 0, KpT, 3, 3 * KpT, nullptr, nullptr, PB);
            gemm_rowsA<3, ERELU>(stream, T, TNUM, TNUM, KpT, st, st, PA, PAelems,
                                 PB, 3 * KpT, F, Cpart, Ct, ld3, 2 * F);
            pack_trans_k<<<dim3(256 / 32, Kp3 / 32), 256, 0, stream>>>(Wd[l], 3 * F, UNITS, 0, Kp3, 3, 3 * Kp3, nullptr, nullptr, PB);
            gemm_rowsA<3, ERELU>(stream, Cd, DNUM, 3 * F, Kp3, nullptr, nullptr, PA, PAelems,
                                 PB, 3 * Kp3, UNITS, Cpart, hd1, UNITS, 0);
            pack_trans_k<<<dim3(256 / 32, Kp3 / 32), 256, 0, stream>>>(Wt[l], 3 * F, UNITS, 0, Kp3, 3, 3 * Kp3, nullptr, nullptr, PB);
            gemm_rowsA<3, ERELU>(stream, Ct, TNUM, 3 * F, Kp3, nullptr, nullptr, PA, PAelems,
                                 PB, 3 * Kp3, UNITS, Cpart, ht1, UNITS, 0);
            hd_in = hd1; ht_in = ht1;
        } else {
            pack_trans_k<<<dim3(256 / 32, KpD / 32), 256, 0, stream>>>(hd_in, DNUM, F, 0, KpD, 2, 2 * KpD, nullptr, nullptr, PB);
            gemm_rowsA<2, ERELU>(stream, D, DNUM, DNUM, KpD, sd, sd, PA, PAelems,
                                 PB, 2 * KpD, F, Cpart, Cd, ld3, 2 * F);
            pack_trans_k<<<dim3(256 / 32, KpT / 32), 256, 0, stream>>>(ht_in, TNUM, F, 0, KpT, 2, 2 * KpT, nullptr, nullptr, PB);
            gemm_rowsA<2, ERELU>(stream, T, TNUM, TNUM, KpT, st, st, PA, PAelems,
                                 PB, 2 * KpT, F, Cpart, Ct, ld3, 2 * F);
            pack_trans_k<<<dim3(256 / 32, Kp3 / 32), 256, 0, stream>>>(Wd[l], 3 * F, UNITS, 0, Kp3, 2, 2 * Kp3, nullptr, nullptr, PB);
            gemm_rowsA<2, ERELU>(stream, Cd, DNUM, 3 * F, Kp3, nullptr, nullptr, PA, PAelems,
                                 PB, 2 * Kp3, UNITS, Cpart, hd2, UNITS, 0);
            pack_trans_k<<<dim3(256 / 32, Kp3 / 32), 256, 0, stream>>>(Wt[l], 3 * F, UNITS, 0, Kp3, 2, 2 * Kp3, nullptr, nullptr, PB);
            gemm_rowsA<2, ERELU>(stream, Ct, TNUM, 3 * F, Kp3, nullptr, nullptr, PA, PAelems,
                                 PB, 2 * Kp3, UNITS, Cpart, ht2, UNITS, 0);
            hd_in = hd2; ht_in = ht2;
        }
    }

    // ---- output CGC on original dense graphs (all 2-split: downstream of every top-k) ----
    {
        int F = UNITS, ld3 = 3 * UNITS, Kp3 = Kp3F1;
        // H_dt = relu(R̂ @ ht)
        pack_trans_k<<<dim3(256 / 32, KpT / 32), 256, 0, stream>>>(ht_in, TNUM, F, 0, KpT, 2, 2 * KpT, nullptr, nullptr, PB);
        gemm_rowsA<2, ERELU>(stream, R, DNUM, TNUM, KpT, rdR, rtR, PA, PAelems,
                             PB, 2 * KpT, F, Cpart, Cd, ld3, F);
        // H_td = relu(R̂^T @ hd)
        pack_trans_k<<<dim3(256 / 32, KpD / 32), 256, 0, stream>>>(hd_in, DNUM, F, 0, KpD, 2, 2 * KpD, nullptr, nullptr, PB);
        gemm_transA<2, ERELU>(stream, R, TNUM, DNUM, KpD, rdR, rtR, PA, PAelems,
                              PB, 2 * KpD, F, Cpart, Ct, ld3, F);
        copy_rows_k<<<DNUM, 256, 0, stream>>>(hd_in, F, Cd, ld3);
        copy_rows_k<<<TNUM, 256, 0, stream>>>(ht_in, F, Ct, ld3);
        // H_dd / H_tt (PB still holds the hd / needs re-pack since overwritten)
        gemm_rowsA<2, ERELU>(stream, D, DNUM, DNUM, KpD, sd, sd, PA, PAelems,
                             PB, 2 * KpD, F, Cpart, Cd, ld3, 2 * F);
        pack_trans_k<<<dim3(256 / 32, KpT / 32), 256, 0, stream>>>(ht_in, TNUM, F, 0, KpT, 2, 2 * KpT, nullptr, nullptr, PB);
        gemm_rowsA<2, ERELU>(stream, T, TNUM, TNUM, KpT, st, st, PA, PAelems,
                             PB, 2 * KpT, F, Cpart, Ct, ld3, 2 * F);
        // output projections
        pack_trans_k<<<dim3(256 / 32, Kp3 / 32), 256, 0, stream>>>(Wd[2], 3 * F, UNITS, 0, Kp3, 2, 2 * Kp3, nullptr, nullptr, PB);
        gemm_rowsA<2, ERELU>(stream, Cd, DNUM, 3 * F, Kp3, nullptr, nullptr, PA, PAelems,
                             PB, 2 * Kp3, UNITS, Cpart, hd1, UNITS, 0);
        pack_trans_k<<<dim3(256 / 32, Kp3 / 32), 256, 0, stream>>>(Wt[2], 3 * F, UNITS, 0, Kp3, 2, 2 * Kp3, nullptr, nullptr, PB);
        gemm_rowsA<2, ERELU>(stream, Ct, TNUM, 3 * F, Kp3, nullptr, nullptr, PA, PAelems,
                             PB, 2 * Kp3, UNITS, Cpart, ht1, UNITS, 0);
        // R_pred = sigmoid(hd1 @ ht1^T)
        pack_rows_k<<<2048, 256, 0, stream>>>(ht1, TNUM, UNITS, 0, KpU, 2, 2 * KpU, nullptr, nullptr, PB);
        gemm_rowsA<2, ESIG>(stream, hd1, DNUM, UNITS, KpU, nullptr, nullptr, PA, PAelems,
                            PB, 2 * KpU, TNUM, Cpart, out, TNUM, 0);
    }
}

// Round 4
// 1508.471 us; speedup vs baseline: 3.5179x; 1.0276x over previous
//
#include <hip/hip_runtime.h>
#include <math.h>

#define DNUM 4000
#define TNUM 2000
#define FEAT 256
#define UNITS 200
#define TOPK 10

typedef __attribute__((ext_vector_type(8))) short short8;
typedef __attribute__((ext_vector_type(4))) float f32x4;

enum { ENONE = 0, ERELU = 1, ERELUSC = 2, ESIG = 3 };

typedef unsigned int u32_g __attribute__((address_space(1)));
typedef unsigned int u32_l __attribute__((address_space(3)));

__device__ __forceinline__ unsigned short f2bf(float x) {
    union { float f; unsigned u; } v; v.f = x;
    unsigned r = v.u + 0x7fffu + ((v.u >> 16) & 1u);  // RNE
    return (unsigned short)(r >> 16);
}
__device__ __forceinline__ float bf2f(unsigned short b) {
    union { float f; unsigned u; } v; v.u = ((unsigned)b) << 16; return v.f;
}
__device__ __forceinline__ void ld_lds16(const void* g, void* l) {
    __builtin_amdgcn_global_load_lds((const u32_g*)g, (u32_l*)l, 16, 0, 0);
}

static inline int cdiv(int a, int b) { return (a + b - 1) / b; }

// ---------------- small utility kernels ----------------

__global__ void fill_zero_k(float* __restrict__ p, int n) {
    int i = blockIdx.x * 256 + threadIdx.x;
    if (i < n) p[i] = 0.f;
}

__global__ void rowsum_rsqrt_k(const float* __restrict__ A, int cols, float* __restrict__ out) {
    int r = blockIdx.x;
    int tid = threadIdx.x;
    const float* row = A + (size_t)r * cols;
    float s = 0.f;
    for (int j = tid; j < cols; j += 256) s += row[j];
    __shared__ float red[256];
    red[tid] = s;
    __syncthreads();
    for (int st = 128; st > 0; st >>= 1) {
        if (tid < st) red[tid] += red[tid + st];
        __syncthreads();
    }
    if (tid == 0) {
        float n = red[0];
        out[r] = (n == 0.f) ? 1.f : (1.f / sqrtf(n));
    }
}

__global__ void colsum_partial_k(const float* __restrict__ A, int rows, int cols,
                                 float* __restrict__ out) {
    int j = blockIdx.x * 256 + threadIdx.x;
    if (j >= cols) return;
    int chunk = blockIdx.y, nch = gridDim.y;
    int r0 = (int)((long long)rows * chunk / nch);
    int r1 = (int)((long long)rows * (chunk + 1) / nch);
    float s = 0.f;
    for (int i = r0; i < r1; i++) s += A[(size_t)i * cols + j];
    atomicAdd(&out[j], s);
}

__global__ void rsqrt_safe_k(float* __restrict__ v, int n) {
    int i = blockIdx.x * 256 + threadIdx.x;
    if (i < n) {
        float x = v[i];
        v[i] = (x == 0.f) ? 1.f : (1.f / sqrtf(x));
    }
}

__global__ void copy_rows_k(const float* __restrict__ src, int F,
                            float* __restrict__ dst, int ldc) {
    int i = blockIdx.x;
    for (int f = threadIdx.x; f < F; f += 256)
        dst[(size_t)i * ldc + f] = src[(size_t)i * F + f];
}

// ---------------- top-k ----------------
__global__ void topk_k(const float* __restrict__ S, int cols,
                       float* __restrict__ tv, int* __restrict__ ti,
                       float* __restrict__ rd) {
    int row = blockIdx.x;
    int tid = threadIdx.x;
    const float* srow = S + (size_t)row * cols;
    __shared__ float vals[2048];
    __shared__ float redv[256];
    __shared__ int   redi[256];
    __shared__ float selv[TOPK];
    __shared__ int   seli[TOPK];
    for (int j = tid; j < cols; j += 256) vals[j] = srow[j];
    __syncthreads();
    for (int it = 0; it < TOPK; ++it) {
        float bv = -3.0e38f;
        int bi = 0x7fffffff;
        for (int j = tid; j < cols; j += 256) {
            float v = vals[j];
            if (v > bv || (v == bv && j < bi)) { bv = v; bi = j; }
        }
        redv[tid] = bv; redi[tid] = bi;
        __syncthreads();
        for (int st = 128; st > 0; st >>= 1) {
            if (tid < st) {
                float v2 = redv[tid + st]; int i2 = redi[tid + st];
                if (v2 > redv[tid] || (v2 == redv[tid] && i2 < redi[tid])) {
                    redv[tid] = v2; redi[tid] = i2;
                }
            }
            __syncthreads();
        }
        if (tid == 0) {
            selv[it] = redv[0];
            seli[it] = redi[0];
            vals[redi[0]] = -3.0e38f;
        }
        __syncthreads();
    }
    if (tid < TOPK) {
        tv[(size_t)row * TOPK + tid] = selv[tid];
        ti[(size_t)row * TOPK + tid] = seli[tid];
    }
    if (tid == 0) {
        float s = 0.f;
        for (int m = 0; m < TOPK; m++) s += selv[m];
        rd[row] = (s == 0.f) ? 1.f : (1.f / sqrtf(s));
    }
}

__global__ void scatter_colsum_k(const float* __restrict__ tv, const int* __restrict__ ti,
                                 float* __restrict__ nt, int n) {
    int g = blockIdx.x * 256 + threadIdx.x;
    if (g < n) atomicAdd(&nt[ti[g]], tv[g]);
}

__global__ void gather_hdt_k(const float* __restrict__ tv, const int* __restrict__ ti,
                             const float* __restrict__ rt, const float* __restrict__ rd,
                             const float* __restrict__ ht, int F,
                             float* __restrict__ C, int ldc, int coloff) {
    int i = blockIdx.x;
    int tid = threadIdx.x;
    __shared__ float w[TOPK];
    __shared__ int   id[TOPK];
    if (tid < TOPK) {
        int idx = ti[(size_t)i * TOPK + tid];
        id[tid] = idx;
        w[tid] = tv[(size_t)i * TOPK + tid] * rt[idx];
    }
    __syncthreads();
    float s = rd[i];
    for (int f = tid; f < F; f += 256) {
        float acc = 0.f;
#pragma unroll
        for (int m = 0; m < TOPK; ++m)
            acc += w[m] * ht[(size_t)id[m] * F + f];
        C[(size_t)i * ldc + coloff + f] = fmaxf(s * acc, 0.f);
    }
}

__global__ void scatter_htd_k(const float* __restrict__ tv, const int* __restrict__ ti,
                              const float* __restrict__ rd, const float* __restrict__ hd,
                              int F, float* __restrict__ accT) {
    int i = blockIdx.x;
    int tid = threadIdx.x;
    __shared__ float row[256];
    __shared__ float w[TOPK];
    __shared__ int   id[TOPK];
    for (int f = tid; f < F; f += 256) row[f] = hd[(size_t)i * F + f];
    if (tid < TOPK) {
        id[tid] = ti[(size_t)i * TOPK + tid];
        w[tid] = tv[(size_t)i * TOPK + tid] * rd[i];
    }
    __syncthreads();
    for (int m = 0; m < TOPK; ++m) {
        float wm = w[m];
        int j = id[m];
        for (int f = tid; f < F; f += 256)
            atomicAdd(&accT[(size_t)j * F + f], wm * row[f]);
    }
}

__global__ void finalize_htd_k(const float* __restrict__ accT, const float* __restrict__ rt,
                               int F, float* __restrict__ C, int ldc, int coloff) {
    int j = blockIdx.x;
    float s = rt[j];
    for (int f = threadIdx.x; f < F; f += 256)
        C[(size_t)j * ldc + coloff + f] = fmaxf(s * accT[(size_t)j * F + f], 0.f);
}

// ---------------- bf16-split pack kernels (chunk-aware) ----------------
__global__ void pack_rows_k(const float* __restrict__ X, int Rtot, int C, int r0,
                            int Kp, int NS, int ld,
                            const float* __restrict__ rs, const float* __restrict__ cs,
                            unsigned short* __restrict__ out) {
    int l = blockIdx.x;
    int r = r0 + l;
    unsigned short* orow = out + (size_t)l * ld;
    if (r >= Rtot) {
        for (int c = threadIdx.x; c < NS * Kp; c += 256) orow[c] = 0;
        return;
    }
    float rsc = rs ? rs[r] : 1.f;
    const float* xrow = X + (size_t)r * C;
    for (int c = threadIdx.x; c < Kp; c += 256) {
        float v = 0.f;
        if (c < C) { v = xrow[c] * rsc; if (cs) v *= cs[c]; }
        unsigned short b0 = f2bf(v);
        orow[c] = b0;
        if (NS >= 2) {
            float r1 = v - bf2f(b0);
            unsigned short b1 = f2bf(r1);
            orow[Kp + c] = b1;
            if (NS == 3) orow[2 * Kp + c] = f2bf(r1 - bf2f(b1));
        }
    }
}

__global__ void pack_trans_k(const float* __restrict__ X, int Kact, int Ctot, int c0base,
                             int Kp, int NS, int ld,
                             const float* __restrict__ ks, const float* __restrict__ ns,
                             unsigned short* __restrict__ out) {
    __shared__ float tile[32][33];
    int c0 = blockIdx.x * 32, k0 = blockIdx.y * 32;
    int ci = threadIdx.x & 31, kq = threadIdx.x >> 5;
    for (int i = 0; i < 4; ++i) {
        int k = k0 + kq * 4 + i;
        int cg = c0base + c0 + ci;
        float v = 0.f;
        if (k < Kact && cg < Ctot) {
            v = X[(size_t)k * Ctot + cg];
            if (ks) v *= ks[k];
            if (ns) v *= ns[cg];
        }
        tile[kq * 4 + i][ci] = v;
    }
    __syncthreads();
    int ko = threadIdx.x & 31, cq = threadIdx.x >> 5;
    for (int i = 0; i < 4; ++i) {
        int c = cq * 4 + i;
        float v = tile[ko][c];
        unsigned short b0 = f2bf(v);
        unsigned short* o = out + (size_t)(c0 + c) * ld + (k0 + ko);
        o[0] = b0;
        if (NS >= 2) {
            float r1 = v - bf2f(b0);
            unsigned short b1 = f2bf(r1);
            o[Kp] = b1;
            if (NS == 3) o[2 * Kp] = f2bf(r1 - bf2f(b1));
        }
    }
}

// ---------------- MFMA split-GEMM ----------------
// LDS layout uses a 16B-block XOR swizzle: LDS block (row, b) holds global block
// b ^ ((row>>1)&3). Staging permutes source addresses within each 64B segment
// (coalescing preserved); fragment reads apply the same XOR -> bank-conflict-free.
template <int MAXS, int EPI>
__global__ __launch_bounds__(256) void gemm_bt_k(
    const unsigned short* __restrict__ A, int ldA,
    const unsigned short* __restrict__ B, int ldB,
    int Kp, int ktot, int splits,
    float* __restrict__ Cpart,
    float* __restrict__ dst, int ldc, int coloff,
    int M, int N) {
    __shared__ __align__(16) short As[MAXS][128 * 32];
    __shared__ __align__(16) short Bs[MAXS][128 * 32];
    int tid = threadIdx.x;
    int lane = tid & 63, wid = tid >> 6;
    int wm = wid >> 1, wn = wid & 1;
    int bm = blockIdx.y * 128, bn = blockIdx.x * 128;
    int z = blockIdx.z;
    int kt0 = (int)((long long)ktot * z / splits);
    int kt1 = (int)((long long)ktot * (z + 1) / splits);
    int r_i = lane & 15, quad = lane >> 4;
    int sw = (quad ^ ((r_i >> 1) & 3)) << 3;   // swizzled 8-short block offset for reads
    f32x4 acc[4][4] = {};
    for (int t = kt0; t < kt1; ++t) {
        int kbase = t * 32;
#pragma unroll
        for (int s = 0; s < MAXS; ++s) {
#pragma unroll
            for (int it = 0; it < 2; ++it) {
                int flat = (it * 256 + tid) * 8;
                int row = flat >> 5;
                int blk = (flat >> 3) & 3;
                int ko = ((blk ^ ((row >> 1) & 3)) << 3);
                ld_lds16(A + (size_t)(bm + row) * ldA + s * Kp + kbase + ko, &As[s][flat]);
                ld_lds16(B + (size_t)(bn + row) * ldB + s * Kp + kbase + ko, &Bs[s][flat]);
            }
        }
        __syncthreads();
        short8 af[MAXS][4], bfr[MAXS][4];
#pragma unroll
        for (int s = 0; s < MAXS; ++s)
#pragma unroll
            for (int mi = 0; mi < 4; ++mi) {
                af[s][mi]  = *(const short8*)&As[s][(wm * 64 + mi * 16 + r_i) * 32 + sw];
                bfr[s][mi] = *(const short8*)&Bs[s][(wn * 64 + mi * 16 + r_i) * 32 + sw];
            }
#pragma unroll
        for (int i = 0; i < MAXS; ++i)
#pragma unroll
            for (int j = 0; j < MAXS; ++j) {
                if (i + j >= MAXS) continue;
#pragma unroll
                for (int mi = 0; mi < 4; ++mi)
#pragma unroll
                    for (int ni = 0; ni < 4; ++ni)
                        acc[mi][ni] = __builtin_amdgcn_mfma_f32_16x16x32_bf16(
                            af[i][mi], bfr[j][ni], acc[mi][ni], 0, 0, 0);
            }
        __syncthreads();
    }
#pragma unroll
    for (int mi = 0; mi < 4; ++mi)
#pragma unroll
        for (int ni = 0; ni < 4; ++ni)
#pragma unroll
            for (int r = 0; r < 4; ++r) {
                int gm = bm + wm * 64 + mi * 16 + quad * 4 + r;
                int gn = bn + wn * 64 + ni * 16 + r_i;
                if (gm >= M || gn >= N) continue;
                float v = acc[mi][ni][r];
                if (splits > 1) {
                    Cpart[((size_t)z * M + gm) * N + gn] = v;
                } else {
                    if (EPI == ERELU) v = fmaxf(v, 0.f);
                    else if (EPI == ESIG) v = 1.f / (1.f + expf(-v));
                    dst[(size_t)gm * ldc + coloff + gn] = v;
                }
            }
}

template <int EPI>
__global__ void epi_k(const float* __restrict__ Cpart, int splits, int M, int N,
                      float* __restrict__ dst, int ldc, int coloff) {
    int idx = blockIdx.x * 256 + threadIdx.x;
    if (idx >= M * N) return;
    size_t stride = (size_t)M * N;
    float v = 0.f;
    for (int s = 0; s < splits; ++s) v += Cpart[s * stride + idx];
    int m = idx / N, n = idx - m * N;
    if (EPI == ERELU) v = fmaxf(v, 0.f);
    else if (EPI == ESIG) v = 1.f / (1.f + expf(-v));
    dst[(size_t)m * ldc + coloff + n] = v;
}

// ---------------- host-side chunked GEMM helpers ----------------
static inline int pick_splits(int nt, int mt, int Ma, int N, int ktiles, size_t cpn) {
    int cap = (int)(cpn / ((size_t)Ma * N));
    int s = cdiv(512, nt * mt);           // target >= 512 blocks (2 blocks/CU)
    if (s > cap) s = cap;
    if (s > ktiles) s = ktiles;
    if (s > 16) s = 16;
    if (s < 1) s = 1;
    return s;
}

template <int MAXS, int EPI>
static void gemm_rowsA(hipStream_t s,
                       const float* Asrc, int Mtot, int Kact, int Kp,
                       const float* rsc, const float* csc,
                       unsigned short* PA, size_t PAelems,
                       const unsigned short* Bp, int ldB, int N,
                       float* Cpart, size_t cpn, float* dst, int ldc, int coloff) {
    int ldA = MAXS * Kp;
    int maxCM = (int)((PAelems / (size_t)ldA) / 128) * 128;
    if (maxCM < 128) maxCM = 128;
    int ktiles = Kp / 32;
    for (int r0 = 0; r0 < Mtot; r0 += maxCM) {
        int Mv = (Mtot - r0 < maxCM) ? (Mtot - r0) : maxCM;
        int Ma = cdiv(Mv, 128) * 128;
        pack_rows_k<<<Ma, 256, 0, s>>>(Asrc, Mtot, Kact, r0, Kp, MAXS, ldA, rsc, csc, PA);
        int splits = pick_splits(cdiv(N, 128), Ma / 128, Ma, N, ktiles, cpn);
        dim3 g(cdiv(N, 128), Ma / 128, splits);
        if (splits == 1) {
            gemm_bt_k<MAXS, EPI><<<g, 256, 0, s>>>(PA, ldA, Bp, ldB, Kp, ktiles, 1, nullptr,
                                                   dst + (size_t)r0 * ldc, ldc, coloff, Mv, N);
        } else {
            gemm_bt_k<MAXS, EPI><<<g, 256, 0, s>>>(PA, ldA, Bp, ldB, Kp, ktiles, splits, Cpart,
                                                   nullptr, 0, 0, Mv, N);
            epi_k<EPI><<<cdiv(Mv * N, 256), 256, 0, s>>>(Cpart, splits, Mv, N,
                                                         dst + (size_t)r0 * ldc, ldc, coloff);
        }
    }
}

template <int MAXS, int EPI>
static void gemm_transA(hipStream_t s,
                        const float* Asrc, int Mtot, int Kact, int Kp,
                        const float* ks, const float* ns,
                        unsigned short* PA, size_t PAelems,
                        const unsigned short* Bp, int ldB, int N,
                        float* Cpart, size_t cpn, float* dst, int ldc, int coloff) {
    int ldA = MAXS * Kp;
    int maxCM = (int)((PAelems / (size_t)ldA) / 128) * 128;
    if (maxCM < 128) maxCM = 128;
    int ktiles = Kp / 32;
    for (int r0 = 0; r0 < Mtot; r0 += maxCM) {
        int Mv = (Mtot - r0 < maxCM) ? (Mtot - r0) : maxCM;
        int Ma = cdiv(Mv, 128) * 128;
        pack_trans_k<<<dim3(Ma / 32, ktiles), 256, 0, s>>>(Asrc, Kact, Mtot, r0, Kp, MAXS, ldA,
                                                           ks, ns, PA);
        int splits = pick_splits(cdiv(N, 128), Ma / 128, Ma, N, ktiles, cpn);
        dim3 g(cdiv(N, 128), Ma / 128, splits);
        if (splits == 1) {
            gemm_bt_k<MAXS, EPI><<<g, 256, 0, s>>>(PA, ldA, Bp, ldB, Kp, ktiles, 1, nullptr,
                                                   dst + (size_t)r0 * ldc, ldc, coloff, Mv, N);
        } else {
            gemm_bt_k<MAXS, EPI><<<g, 256, 0, s>>>(PA, ldA, Bp, ldB, Kp, ktiles, splits, Cpart,
                                                   nullptr, 0, 0, Mv, N);
            epi_k<EPI><<<cdiv(Mv * N, 256), 256, 0, s>>>(Cpart, splits, Mv, N,
                                                         dst + (size_t)r0 * ldc, ldc, coloff);
        }
    }
}

// ---------------- fallback fp32 SGEMM (round-1 proven path) ----------------
#define BM 64
#define BN 64
#define BK 16

template <bool TA, bool TB, int EPI>
__global__ __launch_bounds__(256) void gemm_f32_k(
    int M, int N, int K,
    const float* __restrict__ A, int lda,
    const float* __restrict__ B, int ldb,
    float* __restrict__ C, int ldc,
    const float* __restrict__ scaleB,
    const float* __restrict__ scaleC) {
    __shared__ float Asf[BK][BM + 4];
    __shared__ float Bsf[BK][BN + 4];
    int bn = blockIdx.x * BN;
    int bm = blockIdx.y * BM;
    int tid = threadIdx.x;
    int tx = tid & 15;
    int ty = tid >> 4;
    float acc[4][4] = {};
    for (int t = 0; t < K; t += BK) {
#pragma unroll
        for (int it = 0; it < (BM * BK) / 256; ++it) {
            int l = tid + it * 256;
            int k, m;
            if (TA) { k = l / BM; m = l % BM; }
            else    { m = l / BK; k = l % BK; }
            int gm = bm + m, gk = t + k;
            float v = 0.f;
            if (gm < M && gk < K)
                v = TA ? A[(size_t)gk * lda + gm] : A[(size_t)gm * lda + gk];
            Asf[k][m] = v;
        }
#pragma unroll
        for (int it = 0; it < (BN * BK) / 256; ++it) {
            int l = tid + it * 256;
            int k, n;
            if (TB) { n = l / BK; k = l % BK; }
            else    { k = l / BN; n = l % BN; }
            int gn = bn + n, gk = t + k;
            float v = 0.f;
            if (gn < N && gk < K) {
                v = TB ? B[(size_t)gn * ldb + gk] : B[(size_t)gk * ldb + gn];
                if (scaleB) v *= scaleB[gk];
            }
            Bsf[k][n] = v;
        }
        __syncthreads();
#pragma unroll
        for (int kk = 0; kk < BK; ++kk) {
            float a[4], b[4];
#pragma unroll
            for (int i = 0; i < 4; ++i) a[i] = Asf[kk][ty * 4 + i];
#pragma unroll
            for (int j = 0; j < 4; ++j) b[j] = Bsf[kk][tx * 4 + j];
#pragma unroll
            for (int i = 0; i < 4; ++i)
#pragma unroll
                for (int j = 0; j < 4; ++j)
                    acc[i][j] = fmaf(a[i], b[j], acc[i][j]);
        }
        __syncthreads();
    }
#pragma unroll
    for (int i = 0; i < 4; ++i) {
        int gm = bm + ty * 4 + i;
        if (gm >= M) continue;
#pragma unroll
        for (int j = 0; j < 4; ++j) {
            int gn = bn + tx * 4 + j;
            if (gn >= N) continue;
            float v = acc[i][j];
            if (EPI == ERELUSC) v = fmaxf(scaleC[gm] * v, 0.f);
            else if (EPI == ERELU) v = fmaxf(v, 0.f);
            else if (EPI == ESIG) v = 1.f / (1.f + expf(-v));
            C[(size_t)gm * ldc + gn] = v;
        }
    }
}

template <bool TA, bool TB, int EPI>
static inline void launch_gemm_f32(int M, int N, int K,
                                   const float* A, int lda,
                                   const float* B, int ldb,
                                   float* C, int ldc,
                                   const float* sB, const float* sC,
                                   hipStream_t stream) {
    dim3 grid((N + BN - 1) / BN, (M + BM - 1) / BM);
    gemm_f32_k<TA, TB, EPI><<<grid, dim3(256), 0, stream>>>(M, N, K, A, lda, B, ldb, C, ldc, sB, sC);
}

static void run_fp32_path(void* const* d_in, void* d_out, void* d_ws, hipStream_t stream) {
    const float* R   = (const float*)d_in[0];
    const float* D   = (const float*)d_in[1];
    const float* T   = (const float*)d_in[2];
    const float* H_d = (const float*)d_in[3];
    const float* H_t = (const float*)d_in[4];
    const float* W1g[2] = {(const float*)d_in[5], (const float*)d_in[7]};
    const float* W2g[2] = {(const float*)d_in[6], (const float*)d_in[8]};
    const float* Wd[3]  = {(const float*)d_in[9],  (const float*)d_in[11], (const float*)d_in[13]};
    const float* Wt[3]  = {(const float*)d_in[10], (const float*)d_in[12], (const float*)d_in[14]};
    float* out = (float*)d_out;
    float* ws = (float*)d_ws;
    size_t o = 0;
    auto alloc = [&](size_t n) { float* p = ws + o; o += n; return p; };
    float* sd   = alloc(DNUM);
    float* st   = alloc(TNUM);
    float* rdR  = alloc(DNUM);
    float* rtR  = alloc(TNUM);
    float* rd   = alloc(DNUM);
    float* rt   = alloc(TNUM);
    float* hd1  = alloc((size_t)DNUM * UNITS);
    float* ht1  = alloc((size_t)TNUM * UNITS);
    float* hd2  = alloc((size_t)DNUM * UNITS);
    float* ht2  = alloc((size_t)TNUM * UNITS);
    float* GHd  = alloc((size_t)DNUM * UNITS);
    float* GHt  = alloc((size_t)TNUM * UNITS);
    float* tv   = alloc((size_t)DNUM * TOPK);
    int*   ti   = (int*)alloc((size_t)DNUM * TOPK);
    float* accT = alloc((size_t)TNUM * FEAT);
    float* Cd   = alloc((size_t)DNUM * 3 * FEAT);
    float* Ct   = alloc((size_t)TNUM * 3 * FEAT);

    rowsum_rsqrt_k<<<DNUM, 256, 0, stream>>>(D, DNUM, sd);
    rowsum_rsqrt_k<<<TNUM, 256, 0, stream>>>(T, TNUM, st);
    rowsum_rsqrt_k<<<DNUM, 256, 0, stream>>>(R, TNUM, rdR);
    fill_zero_k<<<cdiv(TNUM, 256), 256, 0, stream>>>(rtR, TNUM);
    colsum_partial_k<<<dim3(cdiv(TNUM, 256), 32), 256, 0, stream>>>(R, DNUM, TNUM, rtR);
    rsqrt_safe_k<<<cdiv(TNUM, 256), 256, 0, stream>>>(rtR, TNUM);

    const float* hd_in = H_d;
    const float* ht_in = H_t;
    for (int l = 0; l < 2; ++l) {
        int F = (l == 0) ? FEAT : UNITS;
        int ld3 = 3 * F;
        launch_gemm_f32<false, false, ENONE>(DNUM, UNITS, F, hd_in, F, W1g[l], UNITS, GHd, UNITS, nullptr, nullptr, stream);
        launch_gemm_f32<false, false, ENONE>(TNUM, UNITS, F, ht_in, F, W2g[l], UNITS, GHt, UNITS, nullptr, nullptr, stream);
        launch_gemm_f32<false, true, ESIG>(DNUM, TNUM, UNITS, GHd, UNITS, GHt, UNITS, out, TNUM, nullptr, nullptr, stream);
        topk_k<<<DNUM, 256, 0, stream>>>(out, TNUM, tv, ti, rd);
        fill_zero_k<<<cdiv(TNUM, 256), 256, 0, stream>>>(rt, TNUM);
        scatter_colsum_k<<<cdiv(DNUM * TOPK, 256), 256, 0, stream>>>(tv, ti, rt, DNUM * TOPK);
        rsqrt_safe_k<<<cdiv(TNUM, 256), 256, 0, stream>>>(rt, TNUM);
        gather_hdt_k<<<DNUM, 256, 0, stream>>>(tv, ti, rt, rd, ht_in, F, Cd, ld3, F);
        fill_zero_k<<<cdiv(TNUM * F, 256), 256, 0, stream>>>(accT, TNUM * F);
        scatter_htd_k<<<DNUM, 256, 0, stream>>>(tv, ti, rd, hd_in, F, accT);
        finalize_htd_k<<<TNUM, 256, 0, stream>>>(accT, rt, F, Ct, ld3, F);
        copy_rows_k<<<DNUM, 256, 0, stream>>>(hd_in, F, Cd, ld3);
        copy_rows_k<<<TNUM, 256, 0, stream>>>(ht_in, F, Ct, ld3);
        launch_gemm_f32<false, false, ERELUSC>(DNUM, F, DNUM, D, DNUM, hd_in, F, Cd + 2 * F, ld3, sd, sd, stream);
        launch_gemm_f32<false, false, ERELUSC>(TNUM, F, TNUM, T, TNUM, ht_in, F, Ct + 2 * F, ld3, st, st, stream);
        float* hdo = (l == 0) ? hd1 : hd2;
        float* hto = (l == 0) ? ht1 : ht2;
        launch_gemm_f32<false, false, ERELU>(DNUM, UNITS, 3 * F, Cd, ld3, Wd[l], UNITS, hdo, UNITS, nullptr, nullptr, stream);
        launch_gemm_f32<false, false, ERELU>(TNUM, UNITS, 3 * F, Ct, ld3, Wt[l], UNITS, hto, UNITS, nullptr, nullptr, stream);
        hd_in = hdo;
        ht_in = hto;
    }
    {
        int F = UNITS, ld3 = 3 * UNITS;
        launch_gemm_f32<false, false, ERELUSC>(DNUM, F, TNUM, R, TNUM, ht_in, F, Cd + F, ld3, rtR, rdR, stream);
        launch_gemm_f32<true, false, ERELUSC>(TNUM, F, DNUM, R, TNUM, hd_in, F, Ct + F, ld3, rdR, rtR, stream);
        copy_rows_k<<<DNUM, 256, 0, stream>>>(hd_in, F, Cd, ld3);
        copy_rows_k<<<TNUM, 256, 0, stream>>>(ht_in, F, Ct, ld3);
        launch_gemm_f32<false, false, ERELUSC>(DNUM, F, DNUM, D, DNUM, hd_in, F, Cd + 2 * F, ld3, sd, sd, stream);
        launch_gemm_f32<false, false, ERELUSC>(TNUM, F, TNUM, T, TNUM, ht_in, F, Ct + 2 * F, ld3, st, st, stream);
        launch_gemm_f32<false, false, ERELU>(DNUM, UNITS, 3 * F, Cd, ld3, Wd[2], UNITS, hd1, UNITS, nullptr, nullptr, stream);
        launch_gemm_f32<false, false, ERELU>(TNUM, UNITS, 3 * F, Ct, ld3, Wt[2], UNITS, ht1, UNITS, nullptr, nullptr, stream);
        launch_gemm_f32<false, true, ESIG>(DNUM, TNUM, UNITS, hd1, UNITS, ht1, UNITS, out, TNUM, nullptr, nullptr, stream);
    }
}

// ---------------- main driver ----------------
extern "C" void kernel_launch(void* const* d_in, const int* in_sizes, int n_in,
                              void* d_out, int out_size, void* d_ws, size_t ws_size,
                              hipStream_t stream) {
    (void)in_sizes; (void)n_in; (void)out_size;
    const float* R   = (const float*)d_in[0];
    const float* D   = (const float*)d_in[1];
    const float* T   = (const float*)d_in[2];
    const float* H_d = (const float*)d_in[3];
    const float* H_t = (const float*)d_in[4];
    const float* W1g[2] = {(const float*)d_in[5], (const float*)d_in[7]};
    const float* W2g[2] = {(const float*)d_in[6], (const float*)d_in[8]};
    const float* Wd[3]  = {(const float*)d_in[9],  (const float*)d_in[11], (const float*)d_in[13]};
    const float* Wt[3]  = {(const float*)d_in[10], (const float*)d_in[12], (const float*)d_in[14]};
    float* out = (float*)d_out;   // [4000,2000]; doubles as GL score scratch

    const int KpD = 4000, KpT = 2016, KpU = 224;
    const int KpF0 = 256;
    const int Kp3F0 = 768, Kp3F1 = 608;

    char* base = (char*)d_ws;
    size_t off = 0;
    auto alloc = [&](size_t bytes) -> void* {
        off = (off + 255) & ~(size_t)255;
        void* p = base + off;
        off += bytes;
        return p;
    };
    float* sd   = (float*)alloc(DNUM * 4);
    float* st   = (float*)alloc(TNUM * 4);
    float* rdR  = (float*)alloc(DNUM * 4);
    float* rtR  = (float*)alloc(TNUM * 4);
    float* rdv  = (float*)alloc(DNUM * 4);
    float* rt   = (float*)alloc(TNUM * 4);
    float* hd1  = (float*)alloc((size_t)DNUM * UNITS * 4);
    float* ht1  = (float*)alloc((size_t)TNUM * UNITS * 4);
    float* hd2  = (float*)alloc((size_t)DNUM * UNITS * 4);
    float* ht2  = (float*)alloc((size_t)TNUM * UNITS * 4);
    float* GHd  = (float*)alloc((size_t)DNUM * UNITS * 4);
    float* GHt  = (float*)alloc((size_t)TNUM * UNITS * 4);
    float* tv   = (float*)alloc((size_t)DNUM * TOPK * 4);
    int*   ti   = (int*)alloc((size_t)DNUM * TOPK * 4);
    float* accT = (float*)alloc((size_t)TNUM * FEAT * 4);
    float* Cd   = (float*)alloc((size_t)DNUM * 3 * FEAT * 4);
    float* Ct   = (float*)alloc((size_t)TNUM * 3 * FEAT * 4);
    unsigned short* PB = (unsigned short*)alloc((size_t)3200000 * 2);  // B packs
    // Adaptive split of the remainder between Cpart (split-K partials) and PA.
    off = (off + 255) & ~(size_t)255;
    size_t rem = (ws_size > off) ? ws_size - off : 0;
    const size_t PA_FULL = (size_t)4096 * 12000 * 2;   // full 4096-row 3-split D pack
    const size_t PA_MINB = (size_t)1024 * 12000 * 2;
    const size_t CP_BIG = (size_t)8 * 1024 * 1024 * 4;   // 8M floats
    const size_t CP_SML = (size_t)4 * 1024 * 1024 * 4;   // 4M floats
    size_t cpart_bytes;
    if (rem >= PA_FULL + CP_BIG + 512)      cpart_bytes = CP_BIG;
    else if (rem >= PA_FULL + CP_SML + 512) cpart_bytes = CP_SML;
    else if (rem >= PA_MINB + CP_SML + 512) cpart_bytes = CP_SML;
    else { run_fp32_path(d_in, d_out, d_ws, stream); return; }
    float* Cpart = (float*)alloc(cpart_bytes);
    size_t cpn = cpart_bytes / 4;
    off = (off + 255) & ~(size_t)255;
    unsigned short* PA = (unsigned short*)(base + off);
    size_t PAelems = (ws_size - off) / 2;

    // ---- norm vectors ----
    rowsum_rsqrt_k<<<DNUM, 256, 0, stream>>>(D, DNUM, sd);
    rowsum_rsqrt_k<<<TNUM, 256, 0, stream>>>(T, TNUM, st);
    rowsum_rsqrt_k<<<DNUM, 256, 0, stream>>>(R, TNUM, rdR);
    fill_zero_k<<<cdiv(TNUM, 256), 256, 0, stream>>>(rtR, TNUM);
    colsum_partial_k<<<dim3(cdiv(TNUM, 256), 32), 256, 0, stream>>>(R, DNUM, TNUM, rtR);
    rsqrt_safe_k<<<cdiv(TNUM, 256), 256, 0, stream>>>(rtR, TNUM);

    const float* hd_in = H_d;
    const float* ht_in = H_t;
    for (int l = 0; l < 2; ++l) {
        int F = (l == 0) ? FEAT : UNITS;
        int KpF = (l == 0) ? KpF0 : KpU;
        int Kp3 = (l == 0) ? Kp3F0 : Kp3F1;
        int ld3 = 3 * F;
        // ---- GL scoring (3-split, 6 products: fp32-grade, keeps top-k stable) ----
        pack_trans_k<<<dim3(256 / 32, KpF / 32), 256, 0, stream>>>(W1g[l], F, UNITS, 0, KpF, 3, 3 * KpF, nullptr, nullptr, PB);
        gemm_rowsA<3, ENONE>(stream, hd_in, DNUM, F, KpF, nullptr, nullptr, PA, PAelems,
                             PB, 3 * KpF, UNITS, Cpart, cpn, GHd, UNITS, 0);
        pack_trans_k<<<dim3(256 / 32, KpF / 32), 256, 0, stream>>>(W2g[l], F, UNITS, 0, KpF, 3, 3 * KpF, nullptr, nullptr, PB);
        gemm_rowsA<3, ENONE>(stream, ht_in, TNUM, F, KpF, nullptr, nullptr, PA, PAelems,
                             PB, 3 * KpF, UNITS, Cpart, cpn, GHt, UNITS, 0);
        pack_rows_k<<<2048, 256, 0, stream>>>(GHt, TNUM, UNITS, 0, KpU, 3, 3 * KpU, nullptr, nullptr, PB);
        gemm_rowsA<3, ESIG>(stream, GHd, DNUM, UNITS, KpU, nullptr, nullptr, PA, PAelems,
                            PB, 3 * KpU, TNUM, Cpart, cpn, out, TNUM, 0);
        // ---- top-k + sparse CGC terms ----
        topk_k<<<DNUM, 256, 0, stream>>>(out, TNUM, tv, ti, rdv);
        fill_zero_k<<<cdiv(TNUM, 256), 256, 0, stream>>>(rt, TNUM);
        scatter_colsum_k<<<cdiv(DNUM * TOPK, 256), 256, 0, stream>>>(tv, ti, rt, DNUM * TOPK);
        rsqrt_safe_k<<<cdiv(TNUM, 256), 256, 0, stream>>>(rt, TNUM);
        gather_hdt_k<<<DNUM, 256, 0, stream>>>(tv, ti, rt, rdv, ht_in, F, Cd, ld3, F);
        fill_zero_k<<<cdiv(TNUM * F, 256), 256, 0, stream>>>(accT, TNUM * F);
        scatter_htd_k<<<DNUM, 256, 0, stream>>>(tv, ti, rdv, hd_in, F, accT);
        finalize_htd_k<<<TNUM, 256, 0, stream>>>(accT, rt, F, Ct, ld3, F);
        copy_rows_k<<<DNUM, 256, 0, stream>>>(hd_in, F, Cd, ld3);
        copy_rows_k<<<TNUM, 256, 0, stream>>>(ht_in, F, Ct, ld3);
        // ---- dense graph convs (norms folded into D/T packs) ----
        if (l == 0) {
            pack_trans_k<<<dim3(256 / 32, KpD / 32), 256, 0, stream>>>(hd_in, DNUM, F, 0, KpD, 3, 3 * KpD, nullptr, nullptr, PB);
            gemm_rowsA<3, ERELU>(stream, D, DNUM, DNUM, KpD, sd, sd, PA, PAelems,
                                 PB, 3 * KpD, F, Cpart, cpn, Cd, ld3, 2 * F);
            pack_trans_k<<<dim3(256 / 32, KpT / 32), 256, 0, stream>>>(ht_in, TNUM, F, 0, KpT, 3, 3 * KpT, nullptr, nullptr, PB);
            gemm_rowsA<3, ERELU>(stream, T, TNUM, TNUM, KpT, st, st, PA, PAelems,
                                 PB, 3 * KpT, F, Cpart, cpn, Ct, ld3, 2 * F);
            pack_trans_k<<<dim3(256 / 32, Kp3 / 32), 256, 0, stream>>>(Wd[l], 3 * F, UNITS, 0, Kp3, 3, 3 * Kp3, nullptr, nullptr, PB);
            gemm_rowsA<3, ERELU>(stream, Cd, DNUM, 3 * F, Kp3, nullptr, nullptr, PA, PAelems,
                                 PB, 3 * Kp3, UNITS, Cpart, cpn, hd1, UNITS, 0);
            pack_trans_k<<<dim3(256 / 32, Kp3 / 32), 256, 0, stream>>>(Wt[l], 3 * F, UNITS, 0, Kp3, 3, 3 * Kp3, nullptr, nullptr, PB);
            gemm_rowsA<3, ERELU>(stream, Ct, TNUM, 3 * F, Kp3, nullptr, nullptr, PA, PAelems,
                                 PB, 3 * Kp3, UNITS, Cpart, cpn, ht1, UNITS, 0);
            hd_in = hd1; ht_in = ht1;
        } else {
            pack_trans_k<<<dim3(256 / 32, KpD / 32), 256, 0, stream>>>(hd_in, DNUM, F, 0, KpD, 2, 2 * KpD, nullptr, nullptr, PB);
            gemm_rowsA<2, ERELU>(stream, D, DNUM, DNUM, KpD, sd, sd, PA, PAelems,
                                 PB, 2 * KpD, F, Cpart, cpn, Cd, ld3, 2 * F);
            pack_trans_k<<<dim3(256 / 32, KpT / 32), 256, 0, stream>>>(ht_in, TNUM, F, 0, KpT, 2, 2 * KpT, nullptr, nullptr, PB);
            gemm_rowsA<2, ERELU>(stream, T, TNUM, TNUM, KpT, st, st, PA, PAelems,
                                 PB, 2 * KpT, F, Cpart, cpn, Ct, ld3, 2 * F);
            pack_trans_k<<<dim3(256 / 32, Kp3 / 32), 256, 0, stream>>>(Wd[l], 3 * F, UNITS, 0, Kp3, 2, 2 * Kp3, nullptr, nullptr, PB);
            gemm_rowsA<2, ERELU>(stream, Cd, DNUM, 3 * F, Kp3, nullptr, nullptr, PA, PAelems,
                                 PB, 2 * Kp3, UNITS, Cpart, cpn, hd2, UNITS, 0);
            pack_trans_k<<<dim3(256 / 32, Kp3 / 32), 256, 0, stream>>>(Wt[l], 3 * F, UNITS, 0, Kp3, 2, 2 * Kp3, nullptr, nullptr, PB);
            gemm_rowsA<2, ERELU>(stream, Ct, TNUM, 3 * F, Kp3, nullptr, nullptr, PA, PAelems,
                                 PB, 2 * Kp3, UNITS, Cpart, cpn, ht2, UNITS, 0);
            hd_in = hd2; ht_in = ht2;
        }
    }

    // ---- output CGC on original dense graphs (2-split: downstream of all top-k) ----
    {
        int F = UNITS, ld3 = 3 * UNITS, Kp3 = Kp3F1;
        pack_trans_k<<<dim3(256 / 32, KpT / 32), 256, 0, stream>>>(ht_in, TNUM, F, 0, KpT, 2, 2 * KpT, nullptr, nullptr, PB);
        gemm_rowsA<2, ERELU>(stream, R, DNUM, TNUM, KpT, rdR, rtR, PA, PAelems,
                             PB, 2 * KpT, F, Cpart, cpn, Cd, ld3, F);
        pack_trans_k<<<dim3(256 / 32, KpD / 32), 256, 0, stream>>>(hd_in, DNUM, F, 0, KpD, 2, 2 * KpD, nullptr, nullptr, PB);
        gemm_transA<2, ERELU>(stream, R, TNUM, DNUM, KpD, rdR, rtR, PA, PAelems,
                              PB, 2 * KpD, F, Cpart, cpn, Ct, ld3, F);
        copy_rows_k<<<DNUM, 256, 0, stream>>>(hd_in, F, Cd, ld3);
        copy_rows_k<<<TNUM, 256, 0, stream>>>(ht_in, F, Ct, ld3);
        gemm_rowsA<2, ERELU>(stream, D, DNUM, DNUM, KpD, sd, sd, PA, PAelems,
                             PB, 2 * KpD, F, Cpart, cpn, Cd, ld3, 2 * F);
        pack_trans_k<<<dim3(256 / 32, KpT / 32), 256, 0, stream>>>(ht_in, TNUM, F, 0, KpT, 2, 2 * KpT, nullptr, nullptr, PB);
        gemm_rowsA<2, ERELU>(stream, T, TNUM, TNUM, KpT, st, st, PA, PAelems,
                             PB, 2 * KpT, F, Cpart, cpn, Ct, ld3, 2 * F);
        pack_trans_k<<<dim3(256 / 32, Kp3 / 32), 256, 0, stream>>>(Wd[2], 3 * F, UNITS, 0, Kp3, 2, 2 * Kp3, nullptr, nullptr, PB);
        gemm_rowsA<2, ERELU>(stream, Cd, DNUM, 3 * F, Kp3, nullptr, nullptr, PA, PAelems,
                             PB, 2 * Kp3, UNITS, Cpart, cpn, hd1, UNITS, 0);
        pack_trans_k<<<dim3(256 / 32, Kp3 / 32), 256, 0, stream>>>(Wt[2], 3 * F, UNITS, 0, Kp3, 2, 2 * Kp3, nullptr, nullptr, PB);
        gemm_rowsA<2, ERELU>(stream, Ct, TNUM, 3 * F, Kp3, nullptr, nullptr, PA, PAelems,
                             PB, 2 * Kp3, UNITS, Cpart, cpn, ht1, UNITS, 0);
        // R_pred = sigmoid(hd1 @ ht1^T)
        pack_rows_k<<<2048, 256, 0, stream>>>(ht1, TNUM, UNITS, 0, KpU, 2, 2 * KpU, nullptr, nullptr, PB);
        gemm_rowsA<2, ESIG>(stream, hd1, DNUM, UNITS, KpU, nullptr, nullptr, PA, PAelems,
                            PB, 2 * KpU, TNUM, Cpart, cpn, out, TNUM, 0);
    }
}

// Round 5
// 1475.457 us; speedup vs baseline: 3.5966x; 1.0224x over previous
//
#include <hip/hip_runtime.h>
#include <math.h>

#define DNUM 4000
#define TNUM 2000
#define FEAT 256
#define UNITS 200
#define TOPK 10

typedef __attribute__((ext_vector_type(8))) short short8;
typedef __attribute__((ext_vector_type(4))) float f32x4;
typedef __attribute__((ext_vector_type(4))) unsigned short us4;

enum { ENONE = 0, ERELU = 1, ERELUSC = 2, ESIG = 3 };

typedef unsigned int u32_g __attribute__((address_space(1)));
typedef unsigned int u32_l __attribute__((address_space(3)));

__device__ __forceinline__ unsigned short f2bf(float x) {
    union { float f; unsigned u; } v; v.f = x;
    unsigned r = v.u + 0x7fffu + ((v.u >> 16) & 1u);  // RNE
    return (unsigned short)(r >> 16);
}
__device__ __forceinline__ float bf2f(unsigned short b) {
    union { float f; unsigned u; } v; v.u = ((unsigned)b) << 16; return v.f;
}
__device__ __forceinline__ void ld_lds16(const void* g, void* l) {
    __builtin_amdgcn_global_load_lds((const u32_g*)g, (u32_l*)l, 16, 0, 0);
}

static inline int cdiv(int a, int b) { return (a + b - 1) / b; }

// ---------------- small utility kernels ----------------

__global__ void fill_zero_k(float* __restrict__ p, int n) {
    int i = blockIdx.x * 256 + threadIdx.x;
    if (i < n) p[i] = 0.f;
}

// out[r] = rsqrt(safe(rowsum)); cols must be %4 (4000/2000 are)
__global__ void rowsum_rsqrt_k(const float* __restrict__ A, int cols, float* __restrict__ out) {
    int r = blockIdx.x;
    int tid = threadIdx.x;
    const float* row = A + (size_t)r * cols;
    float s = 0.f;
    for (int j4 = tid * 4; j4 < cols; j4 += 1024) {
        f32x4 x = *(const f32x4*)&row[j4];
        s += x[0] + x[1] + x[2] + x[3];
    }
    __shared__ float red[256];
    red[tid] = s;
    __syncthreads();
    for (int st = 128; st > 0; st >>= 1) {
        if (tid < st) red[tid] += red[tid + st];
        __syncthreads();
    }
    if (tid == 0) {
        float n = red[0];
        out[r] = (n == 0.f) ? 1.f : (1.f / sqrtf(n));
    }
}

__global__ void colsum_partial_k(const float* __restrict__ A, int rows, int cols,
                                 float* __restrict__ out) {
    int j = blockIdx.x * 256 + threadIdx.x;
    if (j >= cols) return;
    int chunk = blockIdx.y, nch = gridDim.y;
    int r0 = (int)((long long)rows * chunk / nch);
    int r1 = (int)((long long)rows * (chunk + 1) / nch);
    float s = 0.f;
    for (int i = r0; i < r1; i++) s += A[(size_t)i * cols + j];
    atomicAdd(&out[j], s);
}

__global__ void rsqrt_safe_k(float* __restrict__ v, int n) {
    int i = blockIdx.x * 256 + threadIdx.x;
    if (i < n) {
        float x = v[i];
        v[i] = (x == 0.f) ? 1.f : (1.f / sqrtf(x));
    }
}

__global__ void copy_rows_k(const float* __restrict__ src, int F,
                            float* __restrict__ dst, int ldc) {
    int i = blockIdx.x;
    for (int f4 = threadIdx.x * 4; f4 < F; f4 += 1024)
        *(f32x4*)&dst[(size_t)i * ldc + f4] = *(const f32x4*)&src[(size_t)i * F + f4];
}

// ---------------- top-k ----------------
__global__ void topk_k(const float* __restrict__ S, int cols,
                       float* __restrict__ tv, int* __restrict__ ti,
                       float* __restrict__ rd) {
    int row = blockIdx.x;
    int tid = threadIdx.x;
    const float* srow = S + (size_t)row * cols;
    __shared__ float vals[2048];
    __shared__ float redv[256];
    __shared__ int   redi[256];
    __shared__ float selv[TOPK];
    __shared__ int   seli[TOPK];
    for (int j = tid; j < cols; j += 256) vals[j] = srow[j];
    __syncthreads();
    for (int it = 0; it < TOPK; ++it) {
        float bv = -3.0e38f;
        int bi = 0x7fffffff;
        for (int j = tid; j < cols; j += 256) {
            float v = vals[j];
            if (v > bv || (v == bv && j < bi)) { bv = v; bi = j; }
        }
        redv[tid] = bv; redi[tid] = bi;
        __syncthreads();
        for (int st = 128; st > 0; st >>= 1) {
            if (tid < st) {
                float v2 = redv[tid + st]; int i2 = redi[tid + st];
                if (v2 > redv[tid] || (v2 == redv[tid] && i2 < redi[tid])) {
                    redv[tid] = v2; redi[tid] = i2;
                }
            }
            __syncthreads();
        }
        if (tid == 0) {
            selv[it] = redv[0];
            seli[it] = redi[0];
            vals[redi[0]] = -3.0e38f;
        }
        __syncthreads();
    }
    if (tid < TOPK) {
        tv[(size_t)row * TOPK + tid] = selv[tid];
        ti[(size_t)row * TOPK + tid] = seli[tid];
    }
    if (tid == 0) {
        float s = 0.f;
        for (int m = 0; m < TOPK; m++) s += selv[m];
        rd[row] = (s == 0.f) ? 1.f : (1.f / sqrtf(s));
    }
}

__global__ void scatter_colsum_k(const float* __restrict__ tv, const int* __restrict__ ti,
                                 float* __restrict__ nt, int n) {
    int g = blockIdx.x * 256 + threadIdx.x;
    if (g < n) atomicAdd(&nt[ti[g]], tv[g]);
}

__global__ void gather_hdt_k(const float* __restrict__ tv, const int* __restrict__ ti,
                             const float* __restrict__ rt, const float* __restrict__ rd,
                             const float* __restrict__ ht, int F,
                             float* __restrict__ C, int ldc, int coloff) {
    int i = blockIdx.x;
    int tid = threadIdx.x;
    __shared__ float w[TOPK];
    __shared__ int   id[TOPK];
    if (tid < TOPK) {
        int idx = ti[(size_t)i * TOPK + tid];
        id[tid] = idx;
        w[tid] = tv[(size_t)i * TOPK + tid] * rt[idx];
    }
    __syncthreads();
    float s = rd[i];
    for (int f = tid; f < F; f += 256) {
        float acc = 0.f;
#pragma unroll
        for (int m = 0; m < TOPK; ++m)
            acc += w[m] * ht[(size_t)id[m] * F + f];
        C[(size_t)i * ldc + coloff + f] = fmaxf(s * acc, 0.f);
    }
}

__global__ void scatter_htd_k(const float* __restrict__ tv, const int* __restrict__ ti,
                              const float* __restrict__ rd, const float* __restrict__ hd,
                              int F, float* __restrict__ accT) {
    int i = blockIdx.x;
    int tid = threadIdx.x;
    __shared__ float row[256];
    __shared__ float w[TOPK];
    __shared__ int   id[TOPK];
    for (int f = tid; f < F; f += 256) row[f] = hd[(size_t)i * F + f];
    if (tid < TOPK) {
        id[tid] = ti[(size_t)i * TOPK + tid];
        w[tid] = tv[(size_t)i * TOPK + tid] * rd[i];
    }
    __syncthreads();
    for (int m = 0; m < TOPK; ++m) {
        float wm = w[m];
        int j = id[m];
        for (int f = tid; f < F; f += 256)
            atomicAdd(&accT[(size_t)j * F + f], wm * row[f]);
    }
}

__global__ void finalize_htd_k(const float* __restrict__ accT, const float* __restrict__ rt,
                               int F, float* __restrict__ C, int ldc, int coloff) {
    int j = blockIdx.x;
    float s = rt[j];
    for (int f = threadIdx.x; f < F; f += 256)
        C[(size_t)j * ldc + coloff + f] = fmaxf(s * accT[(size_t)j * F + f], 0.f);
}

// ---------------- bf16-split pack kernels (vectorized) ----------------
// All Kp, C, ld used here are multiples of 4; bases are 256B-aligned.
__global__ void pack_rows_k(const float* __restrict__ X, int Rtot, int C, int r0,
                            int Kp, int NS, int ld,
                            const float* __restrict__ rs, const float* __restrict__ cs,
                            unsigned short* __restrict__ out) {
    int l = blockIdx.x;
    int r = r0 + l;
    unsigned short* orow = out + (size_t)l * ld;
    if (r >= Rtot) {
        us4 z = {0, 0, 0, 0};
        for (int c4 = threadIdx.x * 4; c4 < NS * Kp; c4 += 1024)
            *(us4*)&orow[c4] = z;
        return;
    }
    float rsc = rs ? rs[r] : 1.f;
    const float* xrow = X + (size_t)r * C;
    for (int c4 = threadIdx.x * 4; c4 < Kp; c4 += 1024) {
        float v[4];
        if (c4 + 4 <= C) {
            f32x4 x = *(const f32x4*)&xrow[c4];
            v[0] = x[0]; v[1] = x[1]; v[2] = x[2]; v[3] = x[3];
        } else {
#pragma unroll
            for (int j = 0; j < 4; ++j) v[j] = (c4 + j < C) ? xrow[c4 + j] : 0.f;
        }
        us4 b0v, b1v, b2v;
#pragma unroll
        for (int j = 0; j < 4; ++j) {
            float val = v[j] * rsc;
            if (cs && c4 + j < C) val *= cs[c4 + j];
            unsigned short b0 = f2bf(val);
            b0v[j] = b0;
            float r1 = val - bf2f(b0);
            unsigned short b1 = f2bf(r1);
            b1v[j] = b1;
            b2v[j] = f2bf(r1 - bf2f(b1));
        }
        *(us4*)&orow[c4] = b0v;
        if (NS >= 2) *(us4*)&orow[Kp + c4] = b1v;
        if (NS == 3) *(us4*)&orow[2 * Kp + c4] = b2v;
    }
}

__global__ void pack_trans_k(const float* __restrict__ X, int Kact, int Ctot, int c0base,
                             int Kp, int NS, int ld,
                             const float* __restrict__ ks, const float* __restrict__ ns,
                             unsigned short* __restrict__ out) {
    __shared__ float tile[32][33];
    int c0 = blockIdx.x * 32, k0 = blockIdx.y * 32;
    int ci = threadIdx.x & 31, kq = threadIdx.x >> 5;
    for (int i = 0; i < 4; ++i) {
        int k = k0 + kq * 4 + i;
        int cg = c0base + c0 + ci;
        float v = 0.f;
        if (k < Kact && cg < Ctot) {
            v = X[(size_t)k * Ctot + cg];
            if (ks) v *= ks[k];
            if (ns) v *= ns[cg];
        }
        tile[kq * 4 + i][ci] = v;
    }
    __syncthreads();
    // thread (cl, kq) emits 4 consecutive k for one output row c -> ushort4 stores
    int cl = threadIdx.x & 31, kq2 = threadIdx.x >> 5;
    us4 b0v, b1v, b2v;
#pragma unroll
    for (int i = 0; i < 4; ++i) {
        float v = tile[kq2 * 4 + i][cl];
        unsigned short b0 = f2bf(v);
        b0v[i] = b0;
        float r1 = v - bf2f(b0);
        unsigned short b1 = f2bf(r1);
        b1v[i] = b1;
        b2v[i] = f2bf(r1 - bf2f(b1));
    }
    unsigned short* o = out + (size_t)(c0 + cl) * ld + (k0 + kq2 * 4);
    *(us4*)&o[0] = b0v;
    if (NS >= 2) *(us4*)&o[Kp] = b1v;
    if (NS == 3) *(us4*)&o[2 * Kp] = b2v;
}

// ---------------- MFMA split-GEMM (XOR-swizzled LDS, conflict-free) ----------------
template <int MAXS, int EPI>
__global__ __launch_bounds__(256) void gemm_bt_k(
    const unsigned short* __restrict__ A, int ldA,
    const unsigned short* __restrict__ B, int ldB,
    int Kp, int ktot, int splits,
    float* __restrict__ Cpart,
    float* __restrict__ dst, int ldc, int coloff,
    int M, int N) {
    __shared__ __align__(16) short As[MAXS][128 * 32];
    __shared__ __align__(16) short Bs[MAXS][128 * 32];
    int tid = threadIdx.x;
    int lane = tid & 63, wid = tid >> 6;
    int wm = wid >> 1, wn = wid & 1;
    int bm = blockIdx.y * 128, bn = blockIdx.x * 128;
    int z = blockIdx.z;
    int kt0 = (int)((long long)ktot * z / splits);
    int kt1 = (int)((long long)ktot * (z + 1) / splits);
    int r_i = lane & 15, quad = lane >> 4;
    int sw = (quad ^ ((r_i >> 1) & 3)) << 3;
    f32x4 acc[4][4] = {};
    for (int t = kt0; t < kt1; ++t) {
        int kbase = t * 32;
#pragma unroll
        for (int s = 0; s < MAXS; ++s) {
#pragma unroll
            for (int it = 0; it < 2; ++it) {
                int flat = (it * 256 + tid) * 8;
                int row = flat >> 5;
                int blk = (flat >> 3) & 3;
                int ko = ((blk ^ ((row >> 1) & 3)) << 3);
                ld_lds16(A + (size_t)(bm + row) * ldA + s * Kp + kbase + ko, &As[s][flat]);
                ld_lds16(B + (size_t)(bn + row) * ldB + s * Kp + kbase + ko, &Bs[s][flat]);
            }
        }
        __syncthreads();
        short8 af[MAXS][4], bfr[MAXS][4];
#pragma unroll
        for (int s = 0; s < MAXS; ++s)
#pragma unroll
            for (int mi = 0; mi < 4; ++mi) {
                af[s][mi]  = *(const short8*)&As[s][(wm * 64 + mi * 16 + r_i) * 32 + sw];
                bfr[s][mi] = *(const short8*)&Bs[s][(wn * 64 + mi * 16 + r_i) * 32 + sw];
            }
#pragma unroll
        for (int i = 0; i < MAXS; ++i)
#pragma unroll
            for (int j = 0; j < MAXS; ++j) {
                if (i + j >= MAXS) continue;
#pragma unroll
                for (int mi = 0; mi < 4; ++mi)
#pragma unroll
                    for (int ni = 0; ni < 4; ++ni)
                        acc[mi][ni] = __builtin_amdgcn_mfma_f32_16x16x32_bf16(
                            af[i][mi], bfr[j][ni], acc[mi][ni], 0, 0, 0);
            }
        __syncthreads();
    }
#pragma unroll
    for (int mi = 0; mi < 4; ++mi)
#pragma unroll
        for (int ni = 0; ni < 4; ++ni)
#pragma unroll
            for (int r = 0; r < 4; ++r) {
                int gm = bm + wm * 64 + mi * 16 + quad * 4 + r;
                int gn = bn + wn * 64 + ni * 16 + r_i;
                if (gm >= M || gn >= N) continue;
                float v = acc[mi][ni][r];
                if (splits > 1) {
                    Cpart[((size_t)z * M + gm) * N + gn] = v;
                } else {
                    if (EPI == ERELU) v = fmaxf(v, 0.f);
                    else if (EPI == ESIG) v = 1.f / (1.f + expf(-v));
                    dst[(size_t)gm * ldc + coloff + gn] = v;
                }
            }
}

template <int EPI>
__global__ void epi_k(const float* __restrict__ Cpart, int splits, int M, int N,
                      float* __restrict__ dst, int ldc, int coloff) {
    int idx = blockIdx.x * 256 + threadIdx.x;
    if (idx >= M * N) return;
    size_t stride = (size_t)M * N;
    float v = 0.f;
    for (int s = 0; s < splits; ++s) v += Cpart[s * stride + idx];
    int m = idx / N, n = idx - m * N;
    if (EPI == ERELU) v = fmaxf(v, 0.f);
    else if (EPI == ESIG) v = 1.f / (1.f + expf(-v));
    dst[(size_t)m * ldc + coloff + n] = v;
}

// ---------------- host-side GEMM helpers ----------------
static inline int pick_splits(int nt, int mt, int Ma, int N, int ktiles, size_t cpn) {
    int tiles = nt * mt;
    if (tiles >= 256) return 1;
    int cap = (int)(cpn / ((size_t)Ma * N));
    int s = cdiv(768, tiles);                  // target ~3 blocks/CU
    if (s > cap) s = cap;
    if (s > ktiles) s = ktiles;
    if (s > 16) s = 16;
    if (s < 1) s = 1;
    return s;
}

template <int MAXS, int EPI>
static void gemm_packedA(hipStream_t s, const unsigned short* Ap, int ldA,
                         int M, int Kp, const unsigned short* Bp, int ldB, int N,
                         float* Cpart, size_t cpn, float* dst, int ldc, int coloff) {
    int Ma = cdiv(M, 128) * 128;
    int ktiles = Kp / 32;
    int splits = pick_splits(cdiv(N, 128), Ma / 128, Ma, N, ktiles, cpn);
    dim3 g(cdiv(N, 128), Ma / 128, splits);
    if (splits == 1) {
        gemm_bt_k<MAXS, EPI><<<g, 256, 0, s>>>(Ap, ldA, Bp, ldB, Kp, ktiles, 1, nullptr,
                                               dst, ldc, coloff, M, N);
    } else {
        gemm_bt_k<MAXS, EPI><<<g, 256, 0, s>>>(Ap, ldA, Bp, ldB, Kp, ktiles, splits, Cpart,
                                               nullptr, 0, 0, M, N);
        epi_k<EPI><<<cdiv(M * N, 256), 256, 0, s>>>(Cpart, splits, M, N, dst, ldc, coloff);
    }
}

template <int MAXS, int EPI>
static void gemm_rowsA(hipStream_t s,
                       const float* Asrc, int Mtot, int Kact, int Kp,
                       const float* rsc, const float* csc,
                       unsigned short* PA, size_t PAelems,
                       const unsigned short* Bp, int ldB, int N,
                       float* Cpart, size_t cpn, float* dst, int ldc, int coloff) {
    int ldA = MAXS * Kp;
    int maxCM = (int)((PAelems / (size_t)ldA) / 128) * 128;
    if (maxCM < 128) maxCM = 128;
    int ktiles = Kp / 32;
    for (int r0 = 0; r0 < Mtot; r0 += maxCM) {
        int Mv = (Mtot - r0 < maxCM) ? (Mtot - r0) : maxCM;
        int Ma = cdiv(Mv, 128) * 128;
        pack_rows_k<<<Ma, 256, 0, s>>>(Asrc, Mtot, Kact, r0, Kp, MAXS, ldA, rsc, csc, PA);
        int splits = pick_splits(cdiv(N, 128), Ma / 128, Ma, N, ktiles, cpn);
        dim3 g(cdiv(N, 128), Ma / 128, splits);
        if (splits == 1) {
            gemm_bt_k<MAXS, EPI><<<g, 256, 0, s>>>(PA, ldA, Bp, ldB, Kp, ktiles, 1, nullptr,
                                                   dst + (size_t)r0 * ldc, ldc, coloff, Mv, N);
        } else {
            gemm_bt_k<MAXS, EPI><<<g, 256, 0, s>>>(PA, ldA, Bp, ldB, Kp, ktiles, splits, Cpart,
                                                   nullptr, 0, 0, Mv, N);
            epi_k<EPI><<<cdiv(Mv * N, 256), 256, 0, s>>>(Cpart, splits, Mv, N,
                                                         dst + (size_t)r0 * ldc, ldc, coloff);
        }
    }
}

template <int MAXS, int EPI>
static void gemm_transA(hipStream_t s,
                        const float* Asrc, int Mtot, int Kact, int Kp,
                        const float* ks, const float* ns,
                        unsigned short* PA, size_t PAelems,
                        const unsigned short* Bp, int ldB, int N,
                        float* Cpart, size_t cpn, float* dst, int ldc, int coloff) {
    int ldA = MAXS * Kp;
    int maxCM = (int)((PAelems / (size_t)ldA) / 128) * 128;
    if (maxCM < 128) maxCM = 128;
    int ktiles = Kp / 32;
    for (int r0 = 0; r0 < Mtot; r0 += maxCM) {
        int Mv = (Mtot - r0 < maxCM) ? (Mtot - r0) : maxCM;
        int Ma = cdiv(Mv, 128) * 128;
        pack_trans_k<<<dim3(Ma / 32, ktiles), 256, 0, s>>>(Asrc, Kact, Mtot, r0, Kp, MAXS, ldA,
                                                           ks, ns, PA);
        int splits = pick_splits(cdiv(N, 128), Ma / 128, Ma, N, ktiles, cpn);
        dim3 g(cdiv(N, 128), Ma / 128, splits);
        if (splits == 1) {
            gemm_bt_k<MAXS, EPI><<<g, 256, 0, s>>>(PA, ldA, Bp, ldB, Kp, ktiles, 1, nullptr,
                                                   dst + (size_t)r0 * ldc, ldc, coloff, Mv, N);
        } else {
            gemm_bt_k<MAXS, EPI><<<g, 256, 0, s>>>(PA, ldA, Bp, ldB, Kp, ktiles, splits, Cpart,
                                                   nullptr, 0, 0, Mv, N);
            epi_k<EPI><<<cdiv(Mv * N, 256), 256, 0, s>>>(Cpart, splits, Mv, N,
                                                         dst + (size_t)r0 * ldc, ldc, coloff);
        }
    }
}

// ---------------- fallback fp32 SGEMM (round-1 proven path) ----------------
#define BM 64
#define BN 64
#define BK 16

template <bool TA, bool TB, int EPI>
__global__ __launch_bounds__(256) void gemm_f32_k(
    int M, int N, int K,
    const float* __restrict__ A, int lda,
    const float* __restrict__ B, int ldb,
    float* __restrict__ C, int ldc,
    const float* __restrict__ scaleB,
    const float* __restrict__ scaleC) {
    __shared__ float Asf[BK][BM + 4];
    __shared__ float Bsf[BK][BN + 4];
    int bn = blockIdx.x * BN;
    int bm = blockIdx.y * BM;
    int tid = threadIdx.x;
    int tx = tid & 15;
    int ty = tid >> 4;
    float acc[4][4] = {};
    for (int t = 0; t < K; t += BK) {
#pragma unroll
        for (int it = 0; it < (BM * BK) / 256; ++it) {
            int l = tid + it * 256;
            int k, m;
            if (TA) { k = l / BM; m = l % BM; }
            else    { m = l / BK; k = l % BK; }
            int gm = bm + m, gk = t + k;
            float v = 0.f;
            if (gm < M && gk < K)
                v = TA ? A[(size_t)gk * lda + gm] : A[(size_t)gm * lda + gk];
            Asf[k][m] = v;
        }
#pragma unroll
        for (int it = 0; it < (BN * BK) / 256; ++it) {
            int l = tid + it * 256;
            int k, n;
            if (TB) { n = l / BK; k = l % BK; }
            else    { k = l / BN; n = l % BN; }
            int gn = bn + n, gk = t + k;
            float v = 0.f;
            if (gn < N && gk < K) {
                v = TB ? B[(size_t)gn * ldb + gk] : B[(size_t)gk * ldb + gn];
                if (scaleB) v *= scaleB[gk];
            }
            Bsf[k][n] = v;
        }
        __syncthreads();
#pragma unroll
        for (int kk = 0; kk < BK; ++kk) {
            float a[4], b[4];
#pragma unroll
            for (int i = 0; i < 4; ++i) a[i] = Asf[kk][ty * 4 + i];
#pragma unroll
            for (int j = 0; j < 4; ++j) b[j] = Bsf[kk][tx * 4 + j];
#pragma unroll
            for (int i = 0; i < 4; ++i)
#pragma unroll
                for (int j = 0; j < 4; ++j)
                    acc[i][j] = fmaf(a[i], b[j], acc[i][j]);
        }
        __syncthreads();
    }
#pragma unroll
    for (int i = 0; i < 4; ++i) {
        int gm = bm + ty * 4 + i;
        if (gm >= M) continue;
#pragma unroll
        for (int j = 0; j < 4; ++j) {
            int gn = bn + tx * 4 + j;
            if (gn >= N) continue;
            float v = acc[i][j];
            if (EPI == ERELUSC) v = fmaxf(scaleC[gm] * v, 0.f);
            else if (EPI == ERELU) v = fmaxf(v, 0.f);
            else if (EPI == ESIG) v = 1.f / (1.f + expf(-v));
            C[(size_t)gm * ldc + gn] = v;
        }
    }
}

template <bool TA, bool TB, int EPI>
static inline void launch_gemm_f32(int M, int N, int K,
                                   const float* A, int lda,
                                   const float* B, int ldb,
                                   float* C, int ldc,
                                   const float* sB, const float* sC,
                                   hipStream_t stream) {
    dim3 grid((N + BN - 1) / BN, (M + BM - 1) / BM);
    gemm_f32_k<TA, TB, EPI><<<grid, dim3(256), 0, stream>>>(M, N, K, A, lda, B, ldb, C, ldc, sB, sC);
}

static void run_fp32_path(void* const* d_in, void* d_out, void* d_ws, hipStream_t stream) {
    const float* R   = (const float*)d_in[0];
    const float* D   = (const float*)d_in[1];
    const float* T   = (const float*)d_in[2];
    const float* H_d = (const float*)d_in[3];
    const float* H_t = (const float*)d_in[4];
    const float* W1g[2] = {(const float*)d_in[5], (const float*)d_in[7]};
    const float* W2g[2] = {(const float*)d_in[6], (const float*)d_in[8]};
    const float* Wd[3]  = {(const float*)d_in[9],  (const float*)d_in[11], (const float*)d_in[13]};
    const float* Wt[3]  = {(const float*)d_in[10], (const float*)d_in[12], (const float*)d_in[14]};
    float* out = (float*)d_out;
    float* ws = (float*)d_ws;
    size_t o = 0;
    auto alloc = [&](size_t n) { float* p = ws + o; o += n; return p; };
    float* sd   = alloc(DNUM);
    float* st   = alloc(TNUM);
    float* rdR  = alloc(DNUM);
    float* rtR  = alloc(TNUM);
    float* rd   = alloc(DNUM);
    float* rt   = alloc(TNUM);
    float* hd1  = alloc((size_t)DNUM * UNITS);
    float* ht1  = alloc((size_t)TNUM * UNITS);
    float* hd2  = alloc((size_t)DNUM * UNITS);
    float* ht2  = alloc((size_t)TNUM * UNITS);
    float* GHd  = alloc((size_t)DNUM * UNITS);
    float* GHt  = alloc((size_t)TNUM * UNITS);
    float* tv   = alloc((size_t)DNUM * TOPK);
    int*   ti   = (int*)alloc((size_t)DNUM * TOPK);
    float* accT = alloc((size_t)TNUM * FEAT);
    float* Cd   = alloc((size_t)DNUM * 3 * FEAT);
    float* Ct   = alloc((size_t)TNUM * 3 * FEAT);

    rowsum_rsqrt_k<<<DNUM, 256, 0, stream>>>(D, DNUM, sd);
    rowsum_rsqrt_k<<<TNUM, 256, 0, stream>>>(T, TNUM, st);
    rowsum_rsqrt_k<<<DNUM, 256, 0, stream>>>(R, TNUM, rdR);
    fill_zero_k<<<cdiv(TNUM, 256), 256, 0, stream>>>(rtR, TNUM);
    colsum_partial_k<<<dim3(cdiv(TNUM, 256), 32), 256, 0, stream>>>(R, DNUM, TNUM, rtR);
    rsqrt_safe_k<<<cdiv(TNUM, 256), 256, 0, stream>>>(rtR, TNUM);

    const float* hd_in = H_d;
    const float* ht_in = H_t;
    for (int l = 0; l < 2; ++l) {
        int F = (l == 0) ? FEAT : UNITS;
        int ld3 = 3 * F;
        launch_gemm_f32<false, false, ENONE>(DNUM, UNITS, F, hd_in, F, W1g[l], UNITS, GHd, UNITS, nullptr, nullptr, stream);
        launch_gemm_f32<false, false, ENONE>(TNUM, UNITS, F, ht_in, F, W2g[l], UNITS, GHt, UNITS, nullptr, nullptr, stream);
        launch_gemm_f32<false, true, ESIG>(DNUM, TNUM, UNITS, GHd, UNITS, GHt, UNITS, out, TNUM, nullptr, nullptr, stream);
        topk_k<<<DNUM, 256, 0, stream>>>(out, TNUM, tv, ti, rd);
        fill_zero_k<<<cdiv(TNUM, 256), 256, 0, stream>>>(rt, TNUM);
        scatter_colsum_k<<<cdiv(DNUM * TOPK, 256), 256, 0, stream>>>(tv, ti, rt, DNUM * TOPK);
        rsqrt_safe_k<<<cdiv(TNUM, 256), 256, 0, stream>>>(rt, TNUM);
        gather_hdt_k<<<DNUM, 256, 0, stream>>>(tv, ti, rt, rd, ht_in, F, Cd, ld3, F);
        fill_zero_k<<<cdiv(TNUM * F, 256), 256, 0, stream>>>(accT, TNUM * F);
        scatter_htd_k<<<DNUM, 256, 0, stream>>>(tv, ti, rd, hd_in, F, accT);
        finalize_htd_k<<<TNUM, 256, 0, stream>>>(accT, rt, F, Ct, ld3, F);
        copy_rows_k<<<DNUM, 256, 0, stream>>>(hd_in, F, Cd, ld3);
        copy_rows_k<<<TNUM, 256, 0, stream>>>(ht_in, F, Ct, ld3);
        launch_gemm_f32<false, false, ERELUSC>(DNUM, F, DNUM, D, DNUM, hd_in, F, Cd + 2 * F, ld3, sd, sd, stream);
        launch_gemm_f32<false, false, ERELUSC>(TNUM, F, TNUM, T, TNUM, ht_in, F, Ct + 2 * F, ld3, st, st, stream);
        float* hdo = (l == 0) ? hd1 : hd2;
        float* hto = (l == 0) ? ht1 : ht2;
        launch_gemm_f32<false, false, ERELU>(DNUM, UNITS, 3 * F, Cd, ld3, Wd[l], UNITS, hdo, UNITS, nullptr, nullptr, stream);
        launch_gemm_f32<false, false, ERELU>(TNUM, UNITS, 3 * F, Ct, ld3, Wt[l], UNITS, hto, UNITS, nullptr, nullptr, stream);
        hd_in = hdo;
        ht_in = hto;
    }
    {
        int F = UNITS, ld3 = 3 * UNITS;
        launch_gemm_f32<false, false, ERELUSC>(DNUM, F, TNUM, R, TNUM, ht_in, F, Cd + F, ld3, rtR, rdR, stream);
        launch_gemm_f32<true, false, ERELUSC>(TNUM, F, DNUM, R, TNUM, hd_in, F, Ct + F, ld3, rdR, rtR, stream);
        copy_rows_k<<<DNUM, 256, 0, stream>>>(hd_in, F, Cd, ld3);
        copy_rows_k<<<TNUM, 256, 0, stream>>>(ht_in, F, Ct, ld3);
        launch_gemm_f32<false, false, ERELUSC>(DNUM, F, DNUM, D, DNUM, hd_in, F, Cd + 2 * F, ld3, sd, sd, stream);
        launch_gemm_f32<false, false, ERELUSC>(TNUM, F, TNUM, T, TNUM, ht_in, F, Ct + 2 * F, ld3, st, st, stream);
        launch_gemm_f32<false, false, ERELU>(DNUM, UNITS, 3 * F, Cd, ld3, Wd[2], UNITS, hd1, UNITS, nullptr, nullptr, stream);
        launch_gemm_f32<false, false, ERELU>(TNUM, UNITS, 3 * F, Ct, ld3, Wt[2], UNITS, ht1, UNITS, nullptr, nullptr, stream);
        launch_gemm_f32<false, true, ESIG>(DNUM, TNUM, UNITS, hd1, UNITS, ht1, UNITS, out, TNUM, nullptr, nullptr, stream);
    }
}

// ---------------- main driver ----------------
extern "C" void kernel_launch(void* const* d_in, const int* in_sizes, int n_in,
                              void* d_out, int out_size, void* d_ws, size_t ws_size,
                              hipStream_t stream) {
    (void)in_sizes; (void)n_in; (void)out_size;
    const float* R   = (const float*)d_in[0];
    const float* D   = (const float*)d_in[1];
    const float* T   = (const float*)d_in[2];
    const float* H_d = (const float*)d_in[3];
    const float* H_t = (const float*)d_in[4];
    const float* W1g[2] = {(const float*)d_in[5], (const float*)d_in[7]};
    const float* W2g[2] = {(const float*)d_in[6], (const float*)d_in[8]};
    const float* Wd[3]  = {(const float*)d_in[9],  (const float*)d_in[11], (const float*)d_in[13]};
    const float* Wt[3]  = {(const float*)d_in[10], (const float*)d_in[12], (const float*)d_in[14]};
    float* out = (float*)d_out;   // [4000,2000]; doubles as GL score scratch

    const int KpD = 4000, KpT = 2016, KpU = 224;
    const int KpF0 = 256;
    const int Kp3F0 = 768, Kp3F1 = 608;

    char* base = (char*)d_ws;
    size_t off = 0;
    auto alloc = [&](size_t bytes) -> void* {
        off = (off + 255) & ~(size_t)255;
        void* p = base + off;
        off += bytes;
        return p;
    };
    float* sd   = (float*)alloc(DNUM * 4);
    float* st   = (float*)alloc(TNUM * 4);
    float* rdR  = (float*)alloc(DNUM * 4);
    float* rtR  = (float*)alloc(TNUM * 4);
    float* rdv  = (float*)alloc(DNUM * 4);
    float* rt   = (float*)alloc(TNUM * 4);
    float* hd1  = (float*)alloc((size_t)DNUM * UNITS * 4);
    float* ht1  = (float*)alloc((size_t)TNUM * UNITS * 4);
    float* hd2  = (float*)alloc((size_t)DNUM * UNITS * 4);
    float* ht2  = (float*)alloc((size_t)TNUM * UNITS * 4);
    float* GHd  = (float*)alloc((size_t)DNUM * UNITS * 4);
    float* GHt  = (float*)alloc((size_t)TNUM * UNITS * 4);
    float* tv   = (float*)alloc((size_t)DNUM * TOPK * 4);
    int*   ti   = (int*)alloc((size_t)DNUM * TOPK * 4);
    float* accT = (float*)alloc((size_t)TNUM * FEAT * 4);
    float* Cd   = (float*)alloc((size_t)DNUM * 3 * FEAT * 4);
    float* Ct   = (float*)alloc((size_t)TNUM * 3 * FEAT * 4);
    unsigned short* PB = (unsigned short*)alloc((size_t)3200000 * 2);  // B packs

    // ---- tiered workspace plan ----
    const size_t PA_DYN = (size_t)4096 * 4032 * 2;    // 33.0 MB dynamic A packs
    const size_t DP_B   = (size_t)4096 * 12000 * 2;   // persistent 3-split D-hat
    const size_t TP_B   = (size_t)2048 * 6048 * 2;    // persistent 3-split T-hat
    const size_t CP_MIN = (size_t)8 * 1024 * 1024 * 4;
    bool persist = false;
    unsigned short *Dp = nullptr, *Tp = nullptr, *PA = nullptr;
    float* Cpart = nullptr;
    size_t cpn = 0, PAelems = 0;
    {
        size_t aligned_off = (off + 255) & ~(size_t)255;
        if (ws_size >= aligned_off + PA_DYN + DP_B + TP_B + CP_MIN + 1024) {
            persist = true;
            PA = (unsigned short*)alloc(PA_DYN);  PAelems = PA_DYN / 2;
            Dp = (unsigned short*)alloc(DP_B);
            Tp = (unsigned short*)alloc(TP_B);
            off = (off + 255) & ~(size_t)255;
            size_t cb = ws_size - off;
            if (cb > (size_t)64 * 1024 * 1024 * 4) cb = (size_t)64 * 1024 * 1024 * 4;
            Cpart = (float*)(base + off);
            cpn = cb / 4;
        } else {
            // R4 fallback: shared PA, fixed Cpart
            const size_t PA_FULL = (size_t)4096 * 12000 * 2;
            const size_t PA_MINB = (size_t)1024 * 12000 * 2;
            const size_t CP_BIG = (size_t)8 * 1024 * 1024 * 4;
            const size_t CP_SML = (size_t)4 * 1024 * 1024 * 4;
            size_t rem = (ws_size > aligned_off) ? ws_size - aligned_off : 0;
            size_t cpart_bytes;
            if (rem >= PA_FULL + CP_BIG + 512)      cpart_bytes = CP_BIG;
            else if (rem >= PA_FULL + CP_SML + 512) cpart_bytes = CP_SML;
            else if (rem >= PA_MINB + CP_SML + 512) cpart_bytes = CP_SML;
            else { run_fp32_path(d_in, d_out, d_ws, stream); return; }
            Cpart = (float*)alloc(cpart_bytes);
            cpn = cpart_bytes / 4;
            off = (off + 255) & ~(size_t)255;
            PA = (unsigned short*)(base + off);
            PAelems = (ws_size - off) / 2;
        }
    }

    // ---- norm vectors ----
    rowsum_rsqrt_k<<<DNUM, 256, 0, stream>>>(D, DNUM, sd);
    rowsum_rsqrt_k<<<TNUM, 256, 0, stream>>>(T, TNUM, st);
    rowsum_rsqrt_k<<<DNUM, 256, 0, stream>>>(R, TNUM, rdR);
    fill_zero_k<<<cdiv(TNUM, 256), 256, 0, stream>>>(rtR, TNUM);
    colsum_partial_k<<<dim3(cdiv(TNUM, 256), 32), 256, 0, stream>>>(R, DNUM, TNUM, rtR);
    rsqrt_safe_k<<<cdiv(TNUM, 256), 256, 0, stream>>>(rtR, TNUM);

    // ---- persistent packs: D-hat & T-hat once (3-split; 2-split reads segs 0,1) ----
    if (persist) {
        pack_rows_k<<<4096, 256, 0, stream>>>(D, DNUM, DNUM, 0, KpD, 3, 3 * KpD, sd, sd, Dp);
        pack_rows_k<<<2048, 256, 0, stream>>>(T, TNUM, TNUM, 0, KpT, 3, 3 * KpT, st, st, Tp);
    }

    const float* hd_in = H_d;
    const float* ht_in = H_t;
    for (int l = 0; l < 2; ++l) {
        int F = (l == 0) ? FEAT : UNITS;
        int KpF = (l == 0) ? KpF0 : KpU;
        int Kp3 = (l == 0) ? Kp3F0 : Kp3F1;
        int ld3 = 3 * F;
        // ---- GL scoring (3-split, 6 products: fp32-grade, keeps top-k stable) ----
        pack_trans_k<<<dim3(8, KpF / 32), 256, 0, stream>>>(W1g[l], F, UNITS, 0, KpF, 3, 3 * KpF, nullptr, nullptr, PB);
        gemm_rowsA<3, ENONE>(stream, hd_in, DNUM, F, KpF, nullptr, nullptr, PA, PAelems,
                             PB, 3 * KpF, UNITS, Cpart, cpn, GHd, UNITS, 0);
        pack_trans_k<<<dim3(8, KpF / 32), 256, 0, stream>>>(W2g[l], F, UNITS, 0, KpF, 3, 3 * KpF, nullptr, nullptr, PB);
        gemm_rowsA<3, ENONE>(stream, ht_in, TNUM, F, KpF, nullptr, nullptr, PA, PAelems,
                             PB, 3 * KpF, UNITS, Cpart, cpn, GHt, UNITS, 0);
        pack_rows_k<<<2048, 256, 0, stream>>>(GHt, TNUM, UNITS, 0, KpU, 3, 3 * KpU, nullptr, nullptr, PB);
        gemm_rowsA<3, ESIG>(stream, GHd, DNUM, UNITS, KpU, nullptr, nullptr, PA, PAelems,
                            PB, 3 * KpU, TNUM, Cpart, cpn, out, TNUM, 0);
        // ---- top-k + sparse CGC terms ----
        topk_k<<<DNUM, 256, 0, stream>>>(out, TNUM, tv, ti, rdv);
        fill_zero_k<<<cdiv(TNUM, 256), 256, 0, stream>>>(rt, TNUM);
        scatter_colsum_k<<<cdiv(DNUM * TOPK, 256), 256, 0, stream>>>(tv, ti, rt, DNUM * TOPK);
        rsqrt_safe_k<<<cdiv(TNUM, 256), 256, 0, stream>>>(rt, TNUM);
        gather_hdt_k<<<DNUM, 256, 0, stream>>>(tv, ti, rt, rdv, ht_in, F, Cd, ld3, F);
        fill_zero_k<<<cdiv(TNUM * F, 256), 256, 0, stream>>>(accT, TNUM * F);
        scatter_htd_k<<<DNUM, 256, 0, stream>>>(tv, ti, rdv, hd_in, F, accT);
        finalize_htd_k<<<TNUM, 256, 0, stream>>>(accT, rt, F, Ct, ld3, F);
        copy_rows_k<<<DNUM, 256, 0, stream>>>(hd_in, F, Cd, ld3);
        copy_rows_k<<<TNUM, 256, 0, stream>>>(ht_in, F, Ct, ld3);
        // ---- dense graph convs ----
        if (l == 0) {
            pack_trans_k<<<dim3(8, KpD / 32), 256, 0, stream>>>(hd_in, DNUM, F, 0, KpD, 3, 3 * KpD, nullptr, nullptr, PB);
            if (persist)
                gemm_packedA<3, ERELU>(stream, Dp, 3 * KpD, DNUM, KpD, PB, 3 * KpD, F, Cpart, cpn, Cd, ld3, 2 * F);
            else
                gemm_rowsA<3, ERELU>(stream, D, DNUM, DNUM, KpD, sd, sd, PA, PAelems,
                                     PB, 3 * KpD, F, Cpart, cpn, Cd, ld3, 2 * F);
            pack_trans_k<<<dim3(8, KpT / 32), 256, 0, stream>>>(ht_in, TNUM, F, 0, KpT, 3, 3 * KpT, nullptr, nullptr, PB);
            if (persist)
                gemm_packedA<3, ERELU>(stream, Tp, 3 * KpT, TNUM, KpT, PB, 3 * KpT, F, Cpart, cpn, Ct, ld3, 2 * F);
            else
                gemm_rowsA<3, ERELU>(stream, T, TNUM, TNUM, KpT, st, st, PA, PAelems,
                                     PB, 3 * KpT, F, Cpart, cpn, Ct, ld3, 2 * F);
            pack_trans_k<<<dim3(8, Kp3 / 32), 256, 0, stream>>>(Wd[l], 3 * F, UNITS, 0, Kp3, 3, 3 * Kp3, nullptr, nullptr, PB);
            gemm_rowsA<3, ERELU>(stream, Cd, DNUM, 3 * F, Kp3, nullptr, nullptr, PA, PAelems,
                                 PB, 3 * Kp3, UNITS, Cpart, cpn, hd1, UNITS, 0);
            pack_trans_k<<<dim3(8, Kp3 / 32), 256, 0, stream>>>(Wt[l], 3 * F, UNITS, 0, Kp3, 3, 3 * Kp3, nullptr, nullptr, PB);
            gemm_rowsA<3, ERELU>(stream, Ct, TNUM, 3 * F, Kp3, nullptr, nullptr, PA, PAelems,
                                 PB, 3 * Kp3, UNITS, Cpart, cpn, ht1, UNITS, 0);
            hd_in = hd1; ht_in = ht1;
        } else {
            pack_trans_k<<<dim3(8, KpD / 32), 256, 0, stream>>>(hd_in, DNUM, F, 0, KpD, 2, 2 * KpD, nullptr, nullptr, PB);
            if (persist)
                gemm_packedA<2, ERELU>(stream, Dp, 3 * KpD, DNUM, KpD, PB, 2 * KpD, F, Cpart, cpn, Cd, ld3, 2 * F);
            else
                gemm_rowsA<2, ERELU>(stream, D, DNUM, DNUM, KpD, sd, sd, PA, PAelems,
                                     PB, 2 * KpD, F, Cpart, cpn, Cd, ld3, 2 * F);
            pack_trans_k<<<dim3(8, KpT / 32), 256, 0, stream>>>(ht_in, TNUM, F, 0, KpT, 2, 2 * KpT, nullptr, nullptr, PB);
            if (persist)
                gemm_packedA<2, ERELU>(stream, Tp, 3 * KpT, TNUM, KpT, PB, 2 * KpT, F, Cpart, cpn, Ct, ld3, 2 * F);
            else
                gemm_rowsA<2, ERELU>(stream, T, TNUM, TNUM, KpT, st, st, PA, PAelems,
                                     PB, 2 * KpT, F, Cpart, cpn, Ct, ld3, 2 * F);
            pack_trans_k<<<dim3(8, Kp3 / 32), 256, 0, stream>>>(Wd[l], 3 * F, UNITS, 0, Kp3, 2, 2 * Kp3, nullptr, nullptr, PB);
            gemm_rowsA<2, ERELU>(stream, Cd, DNUM, 3 * F, Kp3, nullptr, nullptr, PA, PAelems,
                                 PB, 2 * Kp3, UNITS, Cpart, cpn, hd2, UNITS, 0);
            pack_trans_k<<<dim3(8, Kp3 / 32), 256, 0, stream>>>(Wt[l], 3 * F, UNITS, 0, Kp3, 2, 2 * Kp3, nullptr, nullptr, PB);
            gemm_rowsA<2, ERELU>(stream, Ct, TNUM, 3 * F, Kp3, nullptr, nullptr, PA, PAelems,
                                 PB, 2 * Kp3, UNITS, Cpart, cpn, ht2, UNITS, 0);
            hd_in = hd2; ht_in = ht2;
        }
    }

    // ---- output CGC on original dense graphs (2-split: downstream of all top-k) ----
    {
        int F = UNITS, ld3 = 3 * UNITS, Kp3 = Kp3F1;
        pack_trans_k<<<dim3(8, KpT / 32), 256, 0, stream>>>(ht_in, TNUM, F, 0, KpT, 2, 2 * KpT, nullptr, nullptr, PB);
        gemm_rowsA<2, ERELU>(stream, R, DNUM, TNUM, KpT, rdR, rtR, PA, PAelems,
                             PB, 2 * KpT, F, Cpart, cpn, Cd, ld3, F);
        pack_trans_k<<<dim3(8, KpD / 32), 256, 0, stream>>>(hd_in, DNUM, F, 0, KpD, 2, 2 * KpD, nullptr, nullptr, PB);
        gemm_transA<2, ERELU>(stream, R, TNUM, DNUM, KpD, rdR, rtR, PA, PAelems,
                              PB, 2 * KpD, F, Cpart, cpn, Ct, ld3, F);
        copy_rows_k<<<DNUM, 256, 0, stream>>>(hd_in, F, Cd, ld3);
        copy_rows_k<<<TNUM, 256, 0, stream>>>(ht_in, F, Ct, ld3);
        // H_dd: PB still holds the 2-split hd pack (ld 2*KpD)
        if (persist)
            gemm_packedA<2, ERELU>(stream, Dp, 3 * KpD, DNUM, KpD, PB, 2 * KpD, F, Cpart, cpn, Cd, ld3, 2 * F);
        else
            gemm_rowsA<2, ERELU>(stream, D, DNUM, DNUM, KpD, sd, sd, PA, PAelems,
                                 PB, 2 * KpD, F, Cpart, cpn, Cd, ld3, 2 * F);
        pack_trans_k<<<dim3(8, KpT / 32), 256, 0, stream>>>(ht_in, TNUM, F, 0, KpT, 2, 2 * KpT, nullptr, nullptr, PB);
        if (persist)
            gemm_packedA<2, ERELU>(stream, Tp, 3 * KpT, TNUM, KpT, PB, 2 * KpT, F, Cpart, cpn, Ct, ld3, 2 * F);
        else
            gemm_rowsA<2, ERELU>(stream, T, TNUM, TNUM, KpT, st, st, PA, PAelems,
                                 PB, 2 * KpT, F, Cpart, cpn, Ct, ld3, 2 * F);
        pack_trans_k<<<dim3(8, Kp3 / 32), 256, 0, stream>>>(Wd[2], 3 * F, UNITS, 0, Kp3, 2, 2 * Kp3, nullptr, nullptr, PB);
        gemm_rowsA<2, ERELU>(stream, Cd, DNUM, 3 * F, Kp3, nullptr, nullptr, PA, PAelems,
                             PB, 2 * Kp3, UNITS, Cpart, cpn, hd1, UNITS, 0);
        pack_trans_k<<<dim3(8, Kp3 / 32), 256, 0, stream>>>(Wt[2], 3 * F, UNITS, 0, Kp3, 2, 2 * Kp3, nullptr, nullptr, PB);
        gemm_rowsA<2, ERELU>(stream, Ct, TNUM, 3 * F, Kp3, nullptr, nullptr, PA, PAelems,
                             PB, 2 * Kp3, UNITS, Cpart, cpn, ht1, UNITS, 0);
        // R_pred = sigmoid(hd1 @ ht1^T)
        pack_rows_k<<<2048, 256, 0, stream>>>(ht1, TNUM, UNITS, 0, KpU, 2, 2 * KpU, nullptr, nullptr, PB);
        gemm_rowsA<2, ESIG>(stream, hd1, DNUM, UNITS, KpU, nullptr, nullptr, PA, PAelems,
                            PB, 2 * KpU, TNUM, Cpart, cpn, out, TNUM, 0);
    }
}